// Round 1
// baseline (2881.253 us; speedup 1.0000x reference)
//
#include <hip/hip_runtime.h>
#include <hip/hip_bf16.h>
#include <math.h>

// Problem constants
#define L_SEQ   4096      // F*P = 16*256
#define DMODEL  1024
#define DI      2048
#define NST     16
#define DTRANK  64
#define XDBL_N  96        // DTRANK + 2*NST
#define HID     4096
#define CHUNK   64
#define NCHUNK  64        // L_SEQ / CHUNK
#define POOLED_ROWS 256   // 16 frames * 4 * 4

// ---------------------------------------------------------------------------
// LayerNorm: one block per row, 1024 cols, 256 threads x 4 elems
// ---------------------------------------------------------------------------
__global__ __launch_bounds__(256)
void ln_kernel(const float* __restrict__ x, const float* __restrict__ w,
               const float* __restrict__ b, float* __restrict__ out) {
    int row = blockIdx.x;
    int tid = threadIdx.x;
    const float* xr = x + (size_t)row * DMODEL;
    float v[4];
    float s = 0.f, ss = 0.f;
#pragma unroll
    for (int e = 0; e < 4; e++) {
        v[e] = xr[tid + e * 256];
        s += v[e];
        ss += v[e] * v[e];
    }
#pragma unroll
    for (int off = 32; off > 0; off >>= 1) {
        s  += __shfl_down(s, off);
        ss += __shfl_down(ss, off);
    }
    __shared__ float rs[4], rss[4];
    int wid = tid >> 6;
    if ((tid & 63) == 0) { rs[wid] = s; rss[wid] = ss; }
    __syncthreads();
    s  = rs[0] + rs[1] + rs[2] + rs[3];
    ss = rss[0] + rss[1] + rss[2] + rss[3];
    float mu  = s * (1.f / DMODEL);
    float var = ss * (1.f / DMODEL) - mu * mu;
    float inv = rsqrtf(var + 1e-5f);
    float* outr = out + (size_t)row * DMODEL;
#pragma unroll
    for (int e = 0; e < 4; e++) {
        int col = tid + e * 256;
        outr[col] = (v[e] - mu) * inv * w[col] + b[col];
    }
}

// ---------------------------------------------------------------------------
// Generic fp32 GEMM: C[M,N] = epi(A[M,K] @ B[K,N]); row-major, strided lda/ldb/ldc
// 64x64 tile, 256 threads, 4x4 microtile, K-tile 16
// ---------------------------------------------------------------------------
#define EPI_NONE          0
#define EPI_BIAS_SOFTPLUS 1
#define EPI_RES           2
#define EPI_BIAS_GELU     3
#define EPI_BIAS          4

template <int EPI>
__global__ __launch_bounds__(256)
void gemm_kernel(const float* __restrict__ A, int lda,
                 const float* __restrict__ B, int ldb,
                 float* __restrict__ C, int ldc,
                 int M, int N, int K,
                 const float* __restrict__ bias,
                 const float* __restrict__ res) {
    __shared__ float As[16][65];
    __shared__ float Bs[16][65];
    int tid = threadIdx.x;
    int m0 = blockIdx.y * 64, n0 = blockIdx.x * 64;
    int tx = tid & 15, ty = tid >> 4;
    float acc[4][4] = {};

    for (int k0 = 0; k0 < K; k0 += 16) {
        // A tile: flat = i*16 + kk  (i in 0..63, kk in 0..15)
#pragma unroll
        for (int r = 0; r < 4; r++) {
            int flat = tid + r * 256;
            int i = flat >> 4, kk = flat & 15;
            int row = m0 + i, kc = k0 + kk;
            As[kk][i] = (row < M && kc < K) ? A[(size_t)row * lda + kc] : 0.f;
        }
        // B tile: flat = kk*64 + j
#pragma unroll
        for (int r = 0; r < 4; r++) {
            int flat = tid + r * 256;
            int kk = flat >> 6, j = flat & 63;
            int col = n0 + j, kr = k0 + kk;
            Bs[kk][j] = (col < N && kr < K) ? B[(size_t)kr * ldb + col] : 0.f;
        }
        __syncthreads();
#pragma unroll
        for (int kk = 0; kk < 16; kk++) {
            float a[4], bb[4];
#pragma unroll
            for (int e = 0; e < 4; e++) a[e]  = As[kk][ty * 4 + e];
#pragma unroll
            for (int e = 0; e < 4; e++) bb[e] = Bs[kk][tx * 4 + e];
#pragma unroll
            for (int i2 = 0; i2 < 4; i2++)
#pragma unroll
                for (int j2 = 0; j2 < 4; j2++)
                    acc[i2][j2] += a[i2] * bb[j2];
        }
        __syncthreads();
    }

#pragma unroll
    for (int i2 = 0; i2 < 4; i2++) {
        int row = m0 + ty * 4 + i2;
        if (row >= M) continue;
#pragma unroll
        for (int j2 = 0; j2 < 4; j2++) {
            int col = n0 + tx * 4 + j2;
            if (col >= N) continue;
            float v = acc[i2][j2];
            if (EPI == EPI_BIAS_SOFTPLUS) {
                v += bias[col];
                v = (v > 20.f) ? v : log1pf(__expf(v));
            } else if (EPI == EPI_RES) {
                v += res[(size_t)row * ldc + col];
            } else if (EPI == EPI_BIAS_GELU) {
                v += bias[col];
                v = 0.5f * v * (1.f + erff(v * 0.70710678118654752f));
            } else if (EPI == EPI_BIAS) {
                v += bias[col];
            }
            C[(size_t)row * ldc + col] = v;
        }
    }
}

// ---------------------------------------------------------------------------
// Depthwise causal conv (k=4) + bias + silu.  xin = xz[:, 0:DI] (ld 2*DI)
// ---------------------------------------------------------------------------
__global__ __launch_bounds__(256)
void conv_silu_kernel(const float* __restrict__ xz, const float* __restrict__ cw,
                      const float* __restrict__ cb, float* __restrict__ u) {
    int idx = blockIdx.x * 256 + threadIdx.x;      // over L_SEQ*DI
    if (idx >= L_SEQ * DI) return;
    int ch = idx & (DI - 1);
    int l  = idx >> 11;
    float acc = cb[ch];
#pragma unroll
    for (int k = 0; k < 4; k++) {
        int ls = l - 3 + k;
        if (ls >= 0) acc += cw[ch * 4 + k] * xz[(size_t)ls * (2 * DI) + ch];
    }
    u[idx] = acc / (1.f + __expf(-acc));
}

// ---------------------------------------------------------------------------
// Selective scan, pass 1: per chunk, per d: P[n]=prod a, S[n]=state from h=0
// block: 64 threads (one d each); grid (NCHUNK, DI/64)
// ---------------------------------------------------------------------------
__global__ __launch_bounds__(64)
void scan_pass1(const float* __restrict__ dt, const float* __restrict__ u,
                const float* __restrict__ x_dbl, const float* __restrict__ A_log,
                float* __restrict__ Pw, float* __restrict__ Sw) {
    int c = blockIdx.x;
    int d = blockIdx.y * 64 + threadIdx.x;
    int l0 = c * CHUNK;
    __shared__ float sB[CHUNK * NST];
    for (int i = threadIdx.x; i < CHUNK * NST; i += 64) {
        int l = i >> 4, n = i & 15;
        sB[i] = x_dbl[(size_t)(l0 + l) * XDBL_N + DTRANK + n];
    }
    __syncthreads();
    float Areg[NST], h[NST], P[NST];
#pragma unroll
    for (int n = 0; n < NST; n++) {
        Areg[n] = -__expf(A_log[d * NST + n]);
        h[n] = 0.f; P[n] = 1.f;
    }
    for (int l = 0; l < CHUNK; l++) {
        int gl = l0 + l;
        float dtl = dt[(size_t)gl * DI + d];
        float ul  = u[(size_t)gl * DI + d];
        float du = dtl * ul;
#pragma unroll
        for (int n = 0; n < NST; n++) {
            float a = __expf(dtl * Areg[n]);
            P[n] *= a;
            h[n] = a * h[n] + du * sB[l * NST + n];
        }
    }
    size_t base = (size_t)c * (DI * NST) + (size_t)d * NST;
#pragma unroll
    for (int n = 0; n < NST; n++) { Pw[base + n] = P[n]; Sw[base + n] = h[n]; }
}

// ---------------------------------------------------------------------------
// Selective scan, pass 2: sequential prefix over chunks; 32768 threads (d,n)
// ---------------------------------------------------------------------------
__global__ __launch_bounds__(256)
void scan_pass2(const float* __restrict__ Pw, const float* __restrict__ Sw,
                float* __restrict__ initw) {
    int tid = blockIdx.x * 256 + threadIdx.x;   // 0 .. DI*NST-1
    if (tid >= DI * NST) return;
    float h = 0.f;
    for (int c = 0; c < NCHUNK; c++) {
        size_t idx = (size_t)c * (DI * NST) + tid;
        initw[idx] = h;
        h = Pw[idx] * h + Sw[idx];
    }
}

// ---------------------------------------------------------------------------
// Selective scan, pass 3: replay chunk with proper init, emit
// yy[l,d] = (sum_n h*C + u*D) * silu(z)
// ---------------------------------------------------------------------------
__global__ __launch_bounds__(64)
void scan_pass3(const float* __restrict__ dt, const float* __restrict__ u,
                const float* __restrict__ x_dbl, const float* __restrict__ A_log,
                const float* __restrict__ Dp, const float* __restrict__ initw,
                const float* __restrict__ xz, float* __restrict__ yy) {
    int c = blockIdx.x;
    int d = blockIdx.y * 64 + threadIdx.x;
    int l0 = c * CHUNK;
    __shared__ float sBC[CHUNK * 2 * NST];
    for (int i = threadIdx.x; i < CHUNK * 2 * NST; i += 64) {
        int l = i >> 5, n = i & 31;
        sBC[i] = x_dbl[(size_t)(l0 + l) * XDBL_N + DTRANK + n];
    }
    __syncthreads();
    float Areg[NST], h[NST];
    size_t base = (size_t)c * (DI * NST) + (size_t)d * NST;
#pragma unroll
    for (int n = 0; n < NST; n++) {
        Areg[n] = -__expf(A_log[d * NST + n]);
        h[n] = initw[base + n];
    }
    float Dd = Dp[d];
    for (int l = 0; l < CHUNK; l++) {
        int gl = l0 + l;
        float dtl = dt[(size_t)gl * DI + d];
        float ul  = u[(size_t)gl * DI + d];
        float du = dtl * ul;
        float y = 0.f;
#pragma unroll
        for (int n = 0; n < NST; n++) {
            float a = __expf(dtl * Areg[n]);
            h[n] = a * h[n] + du * sBC[l * 32 + n];
            y += h[n] * sBC[l * 32 + NST + n];
        }
        float zv = xz[(size_t)gl * (2 * DI) + DI + d];
        float sz = zv / (1.f + __expf(-zv));
        yy[(size_t)gl * DI + d] = (y + ul * Dd) * sz;
    }
}

// ---------------------------------------------------------------------------
// AvgPool3d (1,4,4): rows grouped by (frame, i/4, j/4); 16 rows averaged
// ---------------------------------------------------------------------------
__global__ __launch_bounds__(256)
void avgpool_kernel(const float* __restrict__ xf, float* __restrict__ pooled) {
    int idx = blockIdx.x * 256 + threadIdx.x;   // over 256*1024
    if (idx >= POOLED_ROWS * DMODEL) return;
    int dcol = idx & (DMODEL - 1);
    int p = idx >> 10;
    int f  = p >> 4;
    int i4 = (p >> 2) & 3;
    int j4 = p & 3;
    float s = 0.f;
#pragma unroll
    for (int ii = 0; ii < 4; ii++)
#pragma unroll
        for (int jj = 0; jj < 4; jj++) {
            int row = f * 256 + (i4 * 4 + ii) * 16 + (j4 * 4 + jj);
            s += xf[(size_t)row * DMODEL + dcol];
        }
    pooled[idx] = s * (1.f / 16.f);
}

// ---------------------------------------------------------------------------
extern "C" void kernel_launch(void* const* d_in, const int* in_sizes, int n_in,
                              void* d_out, int out_size, void* d_ws, size_t ws_size,
                              hipStream_t stream) {
    const float* vst        = (const float*)d_in[0];
    const float* ln_w       = (const float*)d_in[1];
    const float* ln_b       = (const float*)d_in[2];
    const float* in_proj_w  = (const float*)d_in[3];
    const float* conv_w     = (const float*)d_in[4];
    const float* conv_b     = (const float*)d_in[5];
    const float* x_proj_w   = (const float*)d_in[6];
    const float* dt_proj_w  = (const float*)d_in[7];
    const float* dt_proj_b  = (const float*)d_in[8];
    const float* A_log      = (const float*)d_in[9];
    const float* D_param    = (const float*)d_in[10];
    const float* out_proj_w = (const float*)d_in[11];
    const float* fln_w      = (const float*)d_in[12];
    const float* fln_b      = (const float*)d_in[13];
    const float* mlp_w1     = (const float*)d_in[14];
    const float* mlp_b1     = (const float*)d_in[15];
    const float* mlp_w2     = (const float*)d_in[16];
    const float* mlp_b2     = (const float*)d_in[17];
    float* out = (float*)d_out;

    // Workspace layout (floats)
    float* ws    = (float*)d_ws;
    float* xz    = ws;                      // L*2DI      = 16,777,216
    float* u     = xz + (size_t)L_SEQ * 2 * DI;     // L*DI = 8,388,608
    float* dtb   = u  + (size_t)L_SEQ * DI;         // L*DI = 8,388,608
    float* x_dbl = dtb + (size_t)L_SEQ * DI;        // L*96 = 393,216
    float* xn    = x_dbl + (size_t)L_SEQ * XDBL_N;  // L*DM = 4,194,304
    float* yy    = xn + (size_t)L_SEQ * DMODEL;     // L*DI = 8,388,608
    float* Pw    = yy + (size_t)L_SEQ * DI;         // 2,097,152
    float* Sw    = Pw + (size_t)NCHUNK * DI * NST;  // 2,097,152
    float* initw = Sw + (size_t)NCHUNK * DI * NST;  // 2,097,152
    // reuse dead regions:
    float* x2     = xn;            // xn dead after G1
    float* xf     = dtb;           // dt dead after pass3
    float* pooled = u;             // u dead after pass3
    float* h1     = u + (size_t)POOLED_ROWS * DMODEL;

    dim3 blk256(256);

    // 1) LN1: vst -> xn
    ln_kernel<<<L_SEQ, blk256, 0, stream>>>(vst, ln_w, ln_b, xn);

    // 2) G1: xz = xn @ in_proj_w   [4096,1024]x[1024,4096]
    gemm_kernel<EPI_NONE><<<dim3(4096 / 64, L_SEQ / 64), blk256, 0, stream>>>(
        xn, DMODEL, in_proj_w, 2 * DI, xz, 2 * DI, L_SEQ, 2 * DI, DMODEL, nullptr, nullptr);

    // 3) conv + silu: xz[:, :DI] -> u
    conv_silu_kernel<<<(L_SEQ * DI) / 256, blk256, 0, stream>>>(xz, conv_w, conv_b, u);

    // 4) G2: x_dbl = u @ x_proj_w  [4096,2048]x[2048,96]
    gemm_kernel<EPI_NONE><<<dim3((XDBL_N + 63) / 64, L_SEQ / 64), blk256, 0, stream>>>(
        u, DI, x_proj_w, XDBL_N, x_dbl, XDBL_N, L_SEQ, XDBL_N, DI, nullptr, nullptr);

    // 5) G3: dt = softplus(x_dbl[:, :64] @ dt_proj_w + b)  [4096,64]x[64,2048]
    gemm_kernel<EPI_BIAS_SOFTPLUS><<<dim3(DI / 64, L_SEQ / 64), blk256, 0, stream>>>(
        x_dbl, XDBL_N, dt_proj_w, DI, dtb, DI, L_SEQ, DI, DTRANK, dt_proj_b, nullptr);

    // 6-8) chunked selective scan
    scan_pass1<<<dim3(NCHUNK, DI / 64), dim3(64), 0, stream>>>(
        dtb, u, x_dbl, A_log, Pw, Sw);
    scan_pass2<<<(DI * NST) / 256, blk256, 0, stream>>>(Pw, Sw, initw);
    scan_pass3<<<dim3(NCHUNK, DI / 64), dim3(64), 0, stream>>>(
        dtb, u, x_dbl, A_log, D_param, initw, xz, yy);

    // 9) G4: x2 = vst + yy @ out_proj_w  [4096,2048]x[2048,1024]
    gemm_kernel<EPI_RES><<<dim3(DMODEL / 64, L_SEQ / 64), blk256, 0, stream>>>(
        yy, DI, out_proj_w, DMODEL, x2, DMODEL, L_SEQ, DMODEL, DI, nullptr, vst);

    // 10) LN2: x2 -> xf
    ln_kernel<<<L_SEQ, blk256, 0, stream>>>(x2, fln_w, fln_b, xf);

    // 11) avgpool: xf -> pooled [256,1024]
    avgpool_kernel<<<(POOLED_ROWS * DMODEL) / 256, blk256, 0, stream>>>(xf, pooled);

    // 12) G5: h1 = gelu(pooled @ mlp_w1 + b1)  [256,1024]x[1024,4096]
    gemm_kernel<EPI_BIAS_GELU><<<dim3(HID / 64, POOLED_ROWS / 64), blk256, 0, stream>>>(
        pooled, DMODEL, mlp_w1, HID, h1, HID, POOLED_ROWS, HID, DMODEL, mlp_b1, nullptr);

    // 13) G6: out = h1 @ mlp_w2 + b2  [256,4096]x[4096,4096]
    gemm_kernel<EPI_BIAS><<<dim3(HID / 64, POOLED_ROWS / 64), blk256, 0, stream>>>(
        h1, HID, mlp_w2, HID, out, HID, POOLED_ROWS, HID, HID, mlp_b2, nullptr);
}

// Round 2
// 628.314 us; speedup vs baseline: 4.5857x; 4.5857x over previous
//
#include <hip/hip_runtime.h>
#include <hip/hip_bf16.h>
#include <math.h>

typedef __hip_bfloat16 bf16_t;
typedef __attribute__((ext_vector_type(8))) short short8;
typedef __attribute__((ext_vector_type(4))) float f32x4;

// Problem constants
#define L_SEQ   4096      // F*P = 16*256
#define DMODEL  1024
#define DI      2048
#define NST     16
#define DTRANK  64
#define XDBL_N  96        // DTRANK + 2*NST
#define HID     4096
#define CHUNK   64
#define NCHUNK  64        // L_SEQ / CHUNK
#define POOLED_ROWS 256   // 16 frames * 4 * 4

// ---------------------------------------------------------------------------
// async global->LDS 16B copy (global_load_lds_dwordx4)
// LDS dest is wave-uniform base + lane*16 (pass the wave-uniform base).
// ---------------------------------------------------------------------------
__device__ __forceinline__ void async_load16(const bf16_t* g, bf16_t* l) {
    __builtin_amdgcn_global_load_lds(
        (const __attribute__((address_space(1))) void*)g,
        (__attribute__((address_space(3))) void*)l,
        16, 0, 0);
}

// ---------------------------------------------------------------------------
// Transpose+convert: in fp32 [K,N] row-major -> out bf16 [Npad,K] row-major.
// Rows n in [N, Npad) are zero-filled. K, Npad multiples of 32.
// ---------------------------------------------------------------------------
__global__ __launch_bounds__(256)
void transpose_bf16_kernel(const float* __restrict__ in, int K, int N, int Npad,
                           bf16_t* __restrict__ out) {
    __shared__ float t[32][33];
    int k0 = blockIdx.y * 32, n0 = blockIdx.x * 32;
    int tx = threadIdx.x & 31, ty = threadIdx.x >> 5;   // ty in 0..7
#pragma unroll
    for (int i = 0; i < 4; i++) {
        int k = k0 + ty + i * 8, n = n0 + tx;
        t[ty + i * 8][tx] = (n < N) ? in[(size_t)k * N + n] : 0.f;
    }
    __syncthreads();
#pragma unroll
    for (int i = 0; i < 4; i++) {
        int n = n0 + ty + i * 8, k = k0 + tx;
        if (n < Npad) out[(size_t)n * K + k] = __float2bfloat16(t[tx][ty + i * 8]);
    }
}

// ---------------------------------------------------------------------------
// LayerNorm: one block per row, 1024 cols; templated output dtype
// ---------------------------------------------------------------------------
template <bool BF16OUT>
__global__ __launch_bounds__(256)
void ln_kernel(const float* __restrict__ x, const float* __restrict__ w,
               const float* __restrict__ b, void* __restrict__ out_) {
    int row = blockIdx.x;
    int tid = threadIdx.x;
    const float* xr = x + (size_t)row * DMODEL;
    float v[4];
    float s = 0.f, ss = 0.f;
#pragma unroll
    for (int e = 0; e < 4; e++) {
        v[e] = xr[tid + e * 256];
        s += v[e];
        ss += v[e] * v[e];
    }
#pragma unroll
    for (int off = 32; off > 0; off >>= 1) {
        s  += __shfl_down(s, off);
        ss += __shfl_down(ss, off);
    }
    __shared__ float rs[4], rss[4];
    int wid = tid >> 6;
    if ((tid & 63) == 0) { rs[wid] = s; rss[wid] = ss; }
    __syncthreads();
    s  = rs[0] + rs[1] + rs[2] + rs[3];
    ss = rss[0] + rss[1] + rss[2] + rss[3];
    float mu  = s * (1.f / DMODEL);
    float var = ss * (1.f / DMODEL) - mu * mu;
    float inv = rsqrtf(var + 1e-5f);
#pragma unroll
    for (int e = 0; e < 4; e++) {
        int col = tid + e * 256;
        float o = (v[e] - mu) * inv * w[col] + b[col];
        if (BF16OUT) ((bf16_t*)out_)[(size_t)row * DMODEL + col] = __float2bfloat16(o);
        else         ((float*)out_)[(size_t)row * DMODEL + col] = o;
    }
}

// ---------------------------------------------------------------------------
// bf16 MFMA GEMM: C[M,Nt] = epi(A[M,K] @ Bt[Nt,K]^T)
// 128x128 tile, BK=32, 256 threads (4 waves), each wave 64x64 via 4x4 MFMAs.
// EPI: 0 = store bf16
//      1 = bias+softplus -> bf16
//      2 = +res(fp32)    -> fp32
//      3 = bias+gelu     -> bf16
//      4 = bias          -> fp32
//      5 = store fp32 AND bf16
// ---------------------------------------------------------------------------
template <int EPI>
__global__ __launch_bounds__(256, 2)
void mfma_gemm(const bf16_t* __restrict__ A, int lda,
               const bf16_t* __restrict__ Bt, int ldb,
               int K, int Nstore,
               float* __restrict__ Cf, bf16_t* __restrict__ Cb, int ldc,
               const float* __restrict__ bias, const float* __restrict__ res) {
    __shared__ bf16_t Asl[128 * 32];
    __shared__ bf16_t Bsl[128 * 32];
    const int tid = threadIdx.x;
    const int l = tid & 63, w = tid >> 6;
    const int m0 = blockIdx.y * 128, n0 = blockIdx.x * 128;
    const int wm = (w >> 1) * 64, wn = (w & 1) * 64;

    // staging source: chunk q = r*256 + tid; row = q>>2; kcol = (q&3)*8
    const int srow = tid >> 2;
    const int skc = (tid & 3) * 8;
    const bf16_t* Ag = A + (size_t)(m0 + srow) * lda + skc;
    const bf16_t* Bg = Bt + (size_t)(n0 + srow) * ldb + skc;
    // wave-uniform LDS bases (chunk (r*256 + w*64), 16B chunks = 8 bf16)
    bf16_t* As0 = Asl + (size_t)(w * 64) * 8;
    bf16_t* As1 = Asl + (size_t)(256 + w * 64) * 8;
    bf16_t* Bs0 = Bsl + (size_t)(w * 64) * 8;
    bf16_t* Bs1 = Bsl + (size_t)(256 + w * 64) * 8;

    f32x4 acc[4][4];
#pragma unroll
    for (int i = 0; i < 4; i++)
#pragma unroll
        for (int j = 0; j < 4; j++) acc[i][j] = (f32x4){0.f, 0.f, 0.f, 0.f};

    const short8* Asv = (const short8*)Asl;
    const short8* Bsv = (const short8*)Bsl;
    const int fr = l >> 4;          // quad index 0..3
    const int fc = l & 15;

    for (int k0 = 0; k0 < K; k0 += 32) {
        __syncthreads();
        async_load16(Ag, As0);
        async_load16(Ag + (size_t)64 * lda, As1);
        async_load16(Bg, Bs0);
        async_load16(Bg + (size_t)64 * ldb, Bs1);
        Ag += 32; Bg += 32;
        __syncthreads();

        short8 a[4], b[4];
#pragma unroll
        for (int im = 0; im < 4; im++)
            a[im] = Asv[(wm + im * 16 + fc) * 4 + fr];
#pragma unroll
        for (int in = 0; in < 4; in++)
            b[in] = Bsv[(wn + in * 16 + fc) * 4 + fr];
#pragma unroll
        for (int im = 0; im < 4; im++)
#pragma unroll
            for (int in = 0; in < 4; in++)
                acc[im][in] = __builtin_amdgcn_mfma_f32_16x16x32_bf16(
                    a[im], b[in], acc[im][in], 0, 0, 0);
    }

    // Epilogue: D[row][col]: col = lane&15, row = (lane>>4)*4 + reg
#pragma unroll
    for (int im = 0; im < 4; im++) {
        int mbase = m0 + wm + im * 16 + fr * 4;
#pragma unroll
        for (int in = 0; in < 4; in++) {
            int n = n0 + wn + in * 16 + fc;
            if (n >= Nstore) continue;
            float bv = 0.f;
            if (EPI == 1 || EPI == 3 || EPI == 4) bv = bias[n];
#pragma unroll
            for (int v = 0; v < 4; v++) {
                float x = acc[im][in][v];
                size_t off = (size_t)(mbase + v) * ldc + n;
                if (EPI == 0) {
                    Cb[off] = __float2bfloat16(x);
                } else if (EPI == 1) {
                    x += bv;
                    x = (x > 20.f) ? x : log1pf(__expf(x));
                    Cb[off] = __float2bfloat16(x);
                } else if (EPI == 2) {
                    Cf[off] = x + res[off];
                } else if (EPI == 3) {
                    x += bv;
                    x = 0.5f * x * (1.f + erff(x * 0.70710678118654752f));
                    Cb[off] = __float2bfloat16(x);
                } else if (EPI == 4) {
                    Cf[off] = x + bv;
                } else if (EPI == 5) {
                    Cf[off] = x;
                    Cb[off] = __float2bfloat16(x);
                }
            }
        }
    }
}

// ---------------------------------------------------------------------------
// Depthwise causal conv (k=4) + bias + silu. xin = xz[:, 0:DI] (bf16, ld 2*DI)
// ---------------------------------------------------------------------------
__global__ __launch_bounds__(256)
void conv_silu_kernel(const bf16_t* __restrict__ xz, const float* __restrict__ cw,
                      const float* __restrict__ cb, bf16_t* __restrict__ u) {
    int idx = blockIdx.x * 256 + threadIdx.x;      // over L_SEQ*DI
    if (idx >= L_SEQ * DI) return;
    int ch = idx & (DI - 1);
    int l  = idx >> 11;
    float acc = cb[ch];
#pragma unroll
    for (int k = 0; k < 4; k++) {
        int ls = l - 3 + k;
        if (ls >= 0)
            acc += cw[ch * 4 + k] * __bfloat162float(xz[(size_t)ls * (2 * DI) + ch]);
    }
    u[idx] = __float2bfloat16(acc / (1.f + __expf(-acc)));
}

// ---------------------------------------------------------------------------
// Selective scan pass 1: per chunk/d: P[n]=prod a, S[n]=state from h=0
// ---------------------------------------------------------------------------
__global__ __launch_bounds__(64)
void scan_pass1(const bf16_t* __restrict__ dt, const bf16_t* __restrict__ u,
                const float* __restrict__ x_dbl, const float* __restrict__ A_log,
                float* __restrict__ Pw, float* __restrict__ Sw) {
    int c = blockIdx.x;
    int d = blockIdx.y * 64 + threadIdx.x;
    int l0 = c * CHUNK;
    __shared__ float sB[CHUNK * NST];
    for (int i = threadIdx.x; i < CHUNK * NST; i += 64) {
        int l = i >> 4, n = i & 15;
        sB[i] = x_dbl[(size_t)(l0 + l) * XDBL_N + DTRANK + n];
    }
    __syncthreads();
    float Areg[NST], h[NST], P[NST];
#pragma unroll
    for (int n = 0; n < NST; n++) {
        Areg[n] = -__expf(A_log[d * NST + n]);
        h[n] = 0.f; P[n] = 1.f;
    }
    for (int l = 0; l < CHUNK; l++) {
        int gl = l0 + l;
        float dtl = __bfloat162float(dt[(size_t)gl * DI + d]);
        float ul  = __bfloat162float(u[(size_t)gl * DI + d]);
        float du = dtl * ul;
#pragma unroll
        for (int n = 0; n < NST; n++) {
            float a = __expf(dtl * Areg[n]);
            P[n] *= a;
            h[n] = a * h[n] + du * sB[l * NST + n];
        }
    }
    size_t base = (size_t)c * (DI * NST) + (size_t)d * NST;
#pragma unroll
    for (int n = 0; n < NST; n++) { Pw[base + n] = P[n]; Sw[base + n] = h[n]; }
}

// ---------------------------------------------------------------------------
// Selective scan pass 2: sequential prefix over chunks
// ---------------------------------------------------------------------------
__global__ __launch_bounds__(256)
void scan_pass2(const float* __restrict__ Pw, const float* __restrict__ Sw,
                float* __restrict__ initw) {
    int tid = blockIdx.x * 256 + threadIdx.x;   // 0 .. DI*NST-1
    if (tid >= DI * NST) return;
    float h = 0.f;
    for (int c = 0; c < NCHUNK; c++) {
        size_t idx = (size_t)c * (DI * NST) + tid;
        initw[idx] = h;
        h = Pw[idx] * h + Sw[idx];
    }
}

// ---------------------------------------------------------------------------
// Selective scan pass 3: replay with init, emit yy = (h.C + u*D) * silu(z)
// ---------------------------------------------------------------------------
__global__ __launch_bounds__(64)
void scan_pass3(const bf16_t* __restrict__ dt, const bf16_t* __restrict__ u,
                const float* __restrict__ x_dbl, const float* __restrict__ A_log,
                const float* __restrict__ Dp, const float* __restrict__ initw,
                const bf16_t* __restrict__ xz, bf16_t* __restrict__ yy) {
    int c = blockIdx.x;
    int d = blockIdx.y * 64 + threadIdx.x;
    int l0 = c * CHUNK;
    __shared__ float sBC[CHUNK * 2 * NST];
    for (int i = threadIdx.x; i < CHUNK * 2 * NST; i += 64) {
        int l = i >> 5, n = i & 31;
        sBC[i] = x_dbl[(size_t)(l0 + l) * XDBL_N + DTRANK + n];
    }
    __syncthreads();
    float Areg[NST], h[NST];
    size_t base = (size_t)c * (DI * NST) + (size_t)d * NST;
#pragma unroll
    for (int n = 0; n < NST; n++) {
        Areg[n] = -__expf(A_log[d * NST + n]);
        h[n] = initw[base + n];
    }
    float Dd = Dp[d];
    for (int l = 0; l < CHUNK; l++) {
        int gl = l0 + l;
        float dtl = __bfloat162float(dt[(size_t)gl * DI + d]);
        float ul  = __bfloat162float(u[(size_t)gl * DI + d]);
        float du = dtl * ul;
        float y = 0.f;
#pragma unroll
        for (int n = 0; n < NST; n++) {
            float a = __expf(dtl * Areg[n]);
            h[n] = a * h[n] + du * sBC[l * 32 + n];
            y += h[n] * sBC[l * 32 + NST + n];
        }
        float zv = __bfloat162float(xz[(size_t)gl * (2 * DI) + DI + d]);
        float sz = zv / (1.f + __expf(-zv));
        yy[(size_t)gl * DI + d] = __float2bfloat16((y + ul * Dd) * sz);
    }
}

// ---------------------------------------------------------------------------
// AvgPool3d (1,4,4) -> bf16
// ---------------------------------------------------------------------------
__global__ __launch_bounds__(256)
void avgpool_kernel(const float* __restrict__ xf, bf16_t* __restrict__ pooled) {
    int idx = blockIdx.x * 256 + threadIdx.x;   // over 256*1024
    if (idx >= POOLED_ROWS * DMODEL) return;
    int dcol = idx & (DMODEL - 1);
    int p = idx >> 10;
    int f  = p >> 4;
    int i4 = (p >> 2) & 3;
    int j4 = p & 3;
    float s = 0.f;
#pragma unroll
    for (int ii = 0; ii < 4; ii++)
#pragma unroll
        for (int jj = 0; jj < 4; jj++) {
            int row = f * 256 + (i4 * 4 + ii) * 16 + (j4 * 4 + jj);
            s += xf[(size_t)row * DMODEL + dcol];
        }
    pooled[idx] = __float2bfloat16(s * (1.f / 16.f));
}

// ---------------------------------------------------------------------------
extern "C" void kernel_launch(void* const* d_in, const int* in_sizes, int n_in,
                              void* d_out, int out_size, void* d_ws, size_t ws_size,
                              hipStream_t stream) {
    const float* vst        = (const float*)d_in[0];
    const float* ln_w       = (const float*)d_in[1];
    const float* ln_b       = (const float*)d_in[2];
    const float* in_proj_w  = (const float*)d_in[3];
    const float* conv_w     = (const float*)d_in[4];
    const float* conv_b     = (const float*)d_in[5];
    const float* x_proj_w   = (const float*)d_in[6];
    const float* dt_proj_w  = (const float*)d_in[7];
    const float* dt_proj_b  = (const float*)d_in[8];
    const float* A_log      = (const float*)d_in[9];
    const float* D_param    = (const float*)d_in[10];
    const float* out_proj_w = (const float*)d_in[11];
    const float* fln_w      = (const float*)d_in[12];
    const float* fln_b      = (const float*)d_in[13];
    const float* mlp_w1     = (const float*)d_in[14];
    const float* mlp_b1     = (const float*)d_in[15];
    const float* mlp_w2     = (const float*)d_in[16];
    const float* mlp_b2     = (const float*)d_in[17];
    float* out = (float*)d_out;

    // ---------------- workspace layout ----------------
    char* wsb = (char*)d_ws;
    size_t off = 0;
    auto alloc_bf = [&](size_t n) { bf16_t* p = (bf16_t*)(wsb + off); off += n * 2; return p; };
    auto alloc_f  = [&](size_t n) { float*  p = (float*)(wsb + off); off += n * 4; return p; };

    // bf16 transposed weights
    bf16_t* w1t  = alloc_bf((size_t)(2 * DI) * DMODEL);   // [4096,1024]
    bf16_t* xpt  = alloc_bf((size_t)128 * DI);            // [128,2048] (96 padded)
    bf16_t* dtpt = alloc_bf((size_t)DI * DTRANK);         // [2048,64]
    bf16_t* opt  = alloc_bf((size_t)DMODEL * DI);         // [1024,2048]
    bf16_t* m1t  = alloc_bf((size_t)HID * DMODEL);        // [4096,1024]
    bf16_t* m2t  = alloc_bf((size_t)HID * HID);           // [4096,4096]
    // activations
    bf16_t* xz_bf   = alloc_bf((size_t)L_SEQ * 2 * DI);
    bf16_t* u_bf    = alloc_bf((size_t)L_SEQ * DI);
    bf16_t* dt_bf   = alloc_bf((size_t)L_SEQ * DI);
    bf16_t* xdbl_bf = alloc_bf((size_t)L_SEQ * XDBL_N);
    bf16_t* yy_bf   = alloc_bf((size_t)L_SEQ * DI);
    float*  xdbl_f  = alloc_f((size_t)L_SEQ * XDBL_N);
    float*  Pw      = alloc_f((size_t)NCHUNK * DI * NST);
    float*  Sw      = alloc_f((size_t)NCHUNK * DI * NST);
    float*  initw   = alloc_f((size_t)NCHUNK * DI * NST);
    // aliases over dead regions
    bf16_t* xn_bf   = yy_bf;                // LN1 out; dead before pass3 writes yy
    float*  x2_f    = Pw;                   // P+S dead after pass2 (16.8 MB)
    float*  xf_f    = (float*)u_bf;         // u dead after pass3
    bf16_t* pooled  = dt_bf;                // dt dead after pass3
    bf16_t* h1_bf   = dt_bf + (size_t)POOLED_ROWS * DMODEL;

    dim3 blk256(256);

    // 0) weight transpose+convert (fp32 [K,N] -> bf16 [Npad,K])
    transpose_bf16_kernel<<<dim3((2 * DI) / 32, DMODEL / 32), blk256, 0, stream>>>(
        in_proj_w, DMODEL, 2 * DI, 2 * DI, w1t);
    transpose_bf16_kernel<<<dim3(128 / 32, DI / 32), blk256, 0, stream>>>(
        x_proj_w, DI, XDBL_N, 128, xpt);
    transpose_bf16_kernel<<<dim3(DI / 32, DTRANK / 32), blk256, 0, stream>>>(
        dt_proj_w, DTRANK, DI, DI, dtpt);
    transpose_bf16_kernel<<<dim3(DMODEL / 32, DI / 32), blk256, 0, stream>>>(
        out_proj_w, DI, DMODEL, DMODEL, opt);
    transpose_bf16_kernel<<<dim3(HID / 32, DMODEL / 32), blk256, 0, stream>>>(
        mlp_w1, DMODEL, HID, HID, m1t);
    transpose_bf16_kernel<<<dim3(HID / 32, HID / 32), blk256, 0, stream>>>(
        mlp_w2, HID, HID, HID, m2t);

    // 1) LN1: vst -> xn_bf
    ln_kernel<true><<<L_SEQ, blk256, 0, stream>>>(vst, ln_w, ln_b, xn_bf);

    // 2) G1: xz = xn @ in_proj  -> bf16 [L,4096]
    mfma_gemm<0><<<dim3((2 * DI) / 128, L_SEQ / 128), blk256, 0, stream>>>(
        xn_bf, DMODEL, w1t, DMODEL, DMODEL, 2 * DI, nullptr, xz_bf, 2 * DI, nullptr, nullptr);

    // 3) conv+silu: xz[:,:DI] -> u_bf
    conv_silu_kernel<<<(L_SEQ * DI) / 256, blk256, 0, stream>>>(xz_bf, conv_w, conv_b, u_bf);

    // 4) G2: x_dbl = u @ x_proj -> fp32 + bf16 [L,96]
    mfma_gemm<5><<<dim3(1, L_SEQ / 128), blk256, 0, stream>>>(
        u_bf, DI, xpt, DI, DI, XDBL_N, xdbl_f, xdbl_bf, XDBL_N, nullptr, nullptr);

    // 5) G3: dt = softplus(x_dbl[:,:64] @ dt_proj + b) -> bf16 [L,2048]
    mfma_gemm<1><<<dim3(DI / 128, L_SEQ / 128), blk256, 0, stream>>>(
        xdbl_bf, XDBL_N, dtpt, DTRANK, DTRANK, DI, nullptr, dt_bf, DI, dt_proj_b, nullptr);

    // 6-8) chunked selective scan
    scan_pass1<<<dim3(NCHUNK, DI / 64), dim3(64), 0, stream>>>(
        dt_bf, u_bf, xdbl_f, A_log, Pw, Sw);
    scan_pass2<<<(DI * NST) / 256, blk256, 0, stream>>>(Pw, Sw, initw);
    scan_pass3<<<dim3(NCHUNK, DI / 64), dim3(64), 0, stream>>>(
        dt_bf, u_bf, xdbl_f, A_log, D_param, initw, xz_bf, yy_bf);

    // 9) G4: x2 = vst + yy @ out_proj -> fp32 [L,1024]
    mfma_gemm<2><<<dim3(DMODEL / 128, L_SEQ / 128), blk256, 0, stream>>>(
        yy_bf, DI, opt, DI, DI, DMODEL, x2_f, nullptr, DMODEL, nullptr, vst);

    // 10) LN2: x2 -> xf (fp32)
    ln_kernel<false><<<L_SEQ, blk256, 0, stream>>>(x2_f, fln_w, fln_b, xf_f);

    // 11) avgpool: xf -> pooled bf16 [256,1024]
    avgpool_kernel<<<(POOLED_ROWS * DMODEL) / 256, blk256, 0, stream>>>(xf_f, pooled);

    // 12) G5: h1 = gelu(pooled @ mlp_w1 + b1) -> bf16 [256,4096]
    mfma_gemm<3><<<dim3(HID / 128, POOLED_ROWS / 128), blk256, 0, stream>>>(
        pooled, DMODEL, m1t, DMODEL, DMODEL, HID, nullptr, h1_bf, HID, mlp_b1, nullptr);

    // 13) G6: out = h1 @ mlp_w2 + b2 -> fp32 [256,4096]
    mfma_gemm<4><<<dim3(HID / 128, POOLED_ROWS / 128), blk256, 0, stream>>>(
        h1_bf, HID, m2t, HID, HID, HID, out, nullptr, HID, mlp_b2, nullptr);
}

// Round 3
// 527.157 us; speedup vs baseline: 5.4656x; 1.1919x over previous
//
#include <hip/hip_runtime.h>
#include <hip/hip_bf16.h>
#include <math.h>

typedef __hip_bfloat16 bf16_t;
typedef __attribute__((ext_vector_type(8))) short short8;
typedef __attribute__((ext_vector_type(4))) float f32x4;

// Problem constants
#define L_SEQ   4096      // F*P = 16*256
#define DMODEL  1024
#define DI      2048
#define NST     16
#define DTRANK  64
#define XDBL_N  96        // DTRANK + 2*NST
#define HID     4096
#define CHUNK   64
#define NCHUNK  64        // L_SEQ / CHUNK
#define POOLED_ROWS 256   // 16 frames * 4 * 4

// ---------------------------------------------------------------------------
// async global->LDS 16B copy (global_load_lds_dwordx4)
// LDS dest is wave-uniform base + lane*16 (pass the wave-uniform base).
// ---------------------------------------------------------------------------
__device__ __forceinline__ void async_load16(const bf16_t* g, bf16_t* l) {
    __builtin_amdgcn_global_load_lds(
        (const __attribute__((address_space(1))) void*)g,
        (__attribute__((address_space(3))) void*)l,
        16, 0, 0);
}

// ---------------------------------------------------------------------------
// Transpose+convert: in fp32 [K,N] row-major -> out bf16 [Npad,K] row-major.
// ---------------------------------------------------------------------------
__global__ __launch_bounds__(256)
void transpose_bf16_kernel(const float* __restrict__ in, int K, int N, int Npad,
                           bf16_t* __restrict__ out) {
    __shared__ float t[32][33];
    int k0 = blockIdx.y * 32, n0 = blockIdx.x * 32;
    int tx = threadIdx.x & 31, ty = threadIdx.x >> 5;   // ty in 0..7
#pragma unroll
    for (int i = 0; i < 4; i++) {
        int k = k0 + ty + i * 8, n = n0 + tx;
        t[ty + i * 8][tx] = (n < N) ? in[(size_t)k * N + n] : 0.f;
    }
    __syncthreads();
#pragma unroll
    for (int i = 0; i < 4; i++) {
        int n = n0 + ty + i * 8, k = k0 + tx;
        if (n < Npad) out[(size_t)n * K + k] = __float2bfloat16(t[tx][ty + i * 8]);
    }
}

// ---------------------------------------------------------------------------
// LayerNorm: one block per row, 1024 cols; templated output dtype
// ---------------------------------------------------------------------------
template <bool BF16OUT>
__global__ __launch_bounds__(256)
void ln_kernel(const float* __restrict__ x, const float* __restrict__ w,
               const float* __restrict__ b, void* __restrict__ out_) {
    int row = blockIdx.x;
    int tid = threadIdx.x;
    const float* xr = x + (size_t)row * DMODEL;
    float v[4];
    float s = 0.f, ss = 0.f;
#pragma unroll
    for (int e = 0; e < 4; e++) {
        v[e] = xr[tid + e * 256];
        s += v[e];
        ss += v[e] * v[e];
    }
#pragma unroll
    for (int off = 32; off > 0; off >>= 1) {
        s  += __shfl_down(s, off);
        ss += __shfl_down(ss, off);
    }
    __shared__ float rs[4], rss[4];
    int wid = tid >> 6;
    if ((tid & 63) == 0) { rs[wid] = s; rss[wid] = ss; }
    __syncthreads();
    s  = rs[0] + rs[1] + rs[2] + rs[3];
    ss = rss[0] + rss[1] + rss[2] + rss[3];
    float mu  = s * (1.f / DMODEL);
    float var = ss * (1.f / DMODEL) - mu * mu;
    float inv = rsqrtf(var + 1e-5f);
#pragma unroll
    for (int e = 0; e < 4; e++) {
        int col = tid + e * 256;
        float o = (v[e] - mu) * inv * w[col] + b[col];
        if (BF16OUT) ((bf16_t*)out_)[(size_t)row * DMODEL + col] = __float2bfloat16(o);
        else         ((float*)out_)[(size_t)row * DMODEL + col] = o;
    }
}

// ---------------------------------------------------------------------------
// bf16 MFMA GEMM: C[M,Nt] = epi(A[M,K] @ Bt[Nt,K]^T)
// 128x128 tile, BK=32, 256 threads (4 waves), each wave 64x64 via 4x4 MFMAs.
// EPI: 0 = store bf16
//      1 = bias+softplus -> bf16
//      2 = +res(fp32)    -> fp32
// ---------------------------------------------------------------------------
template <int EPI>
__global__ __launch_bounds__(256, 2)
void mfma_gemm(const bf16_t* __restrict__ A, int lda,
               const bf16_t* __restrict__ Bt, int ldb,
               int K,
               float* __restrict__ Cf, bf16_t* __restrict__ Cb, int ldc,
               const float* __restrict__ bias, const float* __restrict__ res) {
    __shared__ bf16_t Asl[128 * 32];
    __shared__ bf16_t Bsl[128 * 32];
    const int tid = threadIdx.x;
    const int l = tid & 63, w = tid >> 6;
    const int m0 = blockIdx.y * 128, n0 = blockIdx.x * 128;
    const int wm = (w >> 1) * 64, wn = (w & 1) * 64;

    const int srow = tid >> 2;
    const int skc = (tid & 3) * 8;
    const bf16_t* Ag = A + (size_t)(m0 + srow) * lda + skc;
    const bf16_t* Bg = Bt + (size_t)(n0 + srow) * ldb + skc;
    bf16_t* As0 = Asl + (size_t)(w * 64) * 8;
    bf16_t* As1 = Asl + (size_t)(256 + w * 64) * 8;
    bf16_t* Bs0 = Bsl + (size_t)(w * 64) * 8;
    bf16_t* Bs1 = Bsl + (size_t)(256 + w * 64) * 8;

    f32x4 acc[4][4];
#pragma unroll
    for (int i = 0; i < 4; i++)
#pragma unroll
        for (int j = 0; j < 4; j++) acc[i][j] = (f32x4){0.f, 0.f, 0.f, 0.f};

    const short8* Asv = (const short8*)Asl;
    const short8* Bsv = (const short8*)Bsl;
    const int fr = l >> 4;
    const int fc = l & 15;

    for (int k0 = 0; k0 < K; k0 += 32) {
        __syncthreads();
        async_load16(Ag, As0);
        async_load16(Ag + (size_t)64 * lda, As1);
        async_load16(Bg, Bs0);
        async_load16(Bg + (size_t)64 * ldb, Bs1);
        Ag += 32; Bg += 32;
        __syncthreads();

        short8 a[4], b[4];
#pragma unroll
        for (int im = 0; im < 4; im++)
            a[im] = Asv[(wm + im * 16 + fc) * 4 + fr];
#pragma unroll
        for (int in = 0; in < 4; in++)
            b[in] = Bsv[(wn + in * 16 + fc) * 4 + fr];
#pragma unroll
        for (int im = 0; im < 4; im++)
#pragma unroll
            for (int in = 0; in < 4; in++)
                acc[im][in] = __builtin_amdgcn_mfma_f32_16x16x32_bf16(
                    a[im], b[in], acc[im][in], 0, 0, 0);
    }

    // Epilogue: D[row][col]: col = lane&15, row = (lane>>4)*4 + reg
#pragma unroll
    for (int im = 0; im < 4; im++) {
        int mbase = m0 + wm + im * 16 + fr * 4;
#pragma unroll
        for (int in = 0; in < 4; in++) {
            int n = n0 + wn + in * 16 + fc;
            float bv = (EPI == 1) ? bias[n] : 0.f;
#pragma unroll
            for (int v = 0; v < 4; v++) {
                float x = acc[im][in][v];
                size_t off = (size_t)(mbase + v) * ldc + n;
                if (EPI == 0) {
                    Cb[off] = __float2bfloat16(x);
                } else if (EPI == 1) {
                    x += bv;
                    x = (x > 20.f) ? x : log1pf(__expf(x));
                    Cb[off] = __float2bfloat16(x);
                } else if (EPI == 2) {
                    Cf[off] = x + res[off];
                }
            }
        }
    }
}

// ---------------------------------------------------------------------------
// Split-K variant: grid.z = K-split; stores fp32 partials, no epilogue.
// Cpart[z][.][ldc]; pstride = M*ldc
// ---------------------------------------------------------------------------
__global__ __launch_bounds__(256, 2)
void mfma_gemm_splitk(const bf16_t* __restrict__ A, int lda,
                      const bf16_t* __restrict__ Bt, int ldb,
                      int Kper, float* __restrict__ Cpart, int ldc,
                      size_t pstride) {
    __shared__ bf16_t Asl[128 * 32];
    __shared__ bf16_t Bsl[128 * 32];
    const int tid = threadIdx.x;
    const int l = tid & 63, w = tid >> 6;
    const int m0 = blockIdx.y * 128, n0 = blockIdx.x * 128;
    const int wm = (w >> 1) * 64, wn = (w & 1) * 64;
    const int kbase = blockIdx.z * Kper;

    const int srow = tid >> 2;
    const int skc = (tid & 3) * 8;
    const bf16_t* Ag = A + (size_t)(m0 + srow) * lda + kbase + skc;
    const bf16_t* Bg = Bt + (size_t)(n0 + srow) * ldb + kbase + skc;
    bf16_t* As0 = Asl + (size_t)(w * 64) * 8;
    bf16_t* As1 = Asl + (size_t)(256 + w * 64) * 8;
    bf16_t* Bs0 = Bsl + (size_t)(w * 64) * 8;
    bf16_t* Bs1 = Bsl + (size_t)(256 + w * 64) * 8;

    f32x4 acc[4][4];
#pragma unroll
    for (int i = 0; i < 4; i++)
#pragma unroll
        for (int j = 0; j < 4; j++) acc[i][j] = (f32x4){0.f, 0.f, 0.f, 0.f};

    const short8* Asv = (const short8*)Asl;
    const short8* Bsv = (const short8*)Bsl;
    const int fr = l >> 4;
    const int fc = l & 15;

    for (int k0 = 0; k0 < Kper; k0 += 32) {
        __syncthreads();
        async_load16(Ag, As0);
        async_load16(Ag + (size_t)64 * lda, As1);
        async_load16(Bg, Bs0);
        async_load16(Bg + (size_t)64 * ldb, Bs1);
        Ag += 32; Bg += 32;
        __syncthreads();

        short8 a[4], b[4];
#pragma unroll
        for (int im = 0; im < 4; im++)
            a[im] = Asv[(wm + im * 16 + fc) * 4 + fr];
#pragma unroll
        for (int in = 0; in < 4; in++)
            b[in] = Bsv[(wn + in * 16 + fc) * 4 + fr];
#pragma unroll
        for (int im = 0; im < 4; im++)
#pragma unroll
            for (int in = 0; in < 4; in++)
                acc[im][in] = __builtin_amdgcn_mfma_f32_16x16x32_bf16(
                    a[im], b[in], acc[im][in], 0, 0, 0);
    }

    float* Cz = Cpart + (size_t)blockIdx.z * pstride;
#pragma unroll
    for (int im = 0; im < 4; im++) {
        int mbase = m0 + wm + im * 16 + fr * 4;
#pragma unroll
        for (int in = 0; in < 4; in++) {
            int n = n0 + wn + in * 16 + fc;
#pragma unroll
            for (int v = 0; v < 4; v++)
                Cz[(size_t)(mbase + v) * ldc + n] = acc[im][in][v];
        }
    }
}

// ---------------------------------------------------------------------------
// Split-K reduce. EPI: 0 = store fp32+bf16 (no bias); 1 = bias+gelu -> bf16;
//                      2 = bias -> fp32
// ---------------------------------------------------------------------------
template <int S, int EPI>
__global__ __launch_bounds__(256)
void reduce_splitk(const float* __restrict__ part, size_t pstride, int ldp,
                   int M, int N, float* __restrict__ outf, bf16_t* __restrict__ outb,
                   int ldo, const float* __restrict__ bias) {
    int idx = blockIdx.x * 256 + threadIdx.x;
    if (idx >= M * N) return;
    int r = idx / N, c = idx - r * N;
    float s = 0.f;
#pragma unroll
    for (int z = 0; z < S; z++)
        s += part[(size_t)z * pstride + (size_t)r * ldp + c];
    size_t o = (size_t)r * ldo + c;
    if (EPI == 0) {
        outf[o] = s;
        outb[o] = __float2bfloat16(s);
    } else if (EPI == 1) {
        s += bias[c];
        s = 0.5f * s * (1.f + erff(s * 0.70710678118654752f));
        outb[o] = __float2bfloat16(s);
    } else {
        outf[o] = s + bias[c];
    }
}

// ---------------------------------------------------------------------------
// Depthwise causal conv (k=4) + bias + silu. xin = xz[:, 0:DI] (bf16, ld 2*DI)
// ---------------------------------------------------------------------------
__global__ __launch_bounds__(256)
void conv_silu_kernel(const bf16_t* __restrict__ xz, const float* __restrict__ cw,
                      const float* __restrict__ cb, bf16_t* __restrict__ u) {
    int idx = blockIdx.x * 256 + threadIdx.x;      // over L_SEQ*DI
    if (idx >= L_SEQ * DI) return;
    int ch = idx & (DI - 1);
    int l  = idx >> 11;
    float acc = cb[ch];
#pragma unroll
    for (int k = 0; k < 4; k++) {
        int ls = l - 3 + k;
        if (ls >= 0)
            acc += cw[ch * 4 + k] * __bfloat162float(xz[(size_t)ls * (2 * DI) + ch]);
    }
    u[idx] = __float2bfloat16(acc / (1.f + __expf(-acc)));
}

// ---------------------------------------------------------------------------
// Selective scan pass 1: per chunk/d: P[n]=prod a, S[n]=state from h=0
// ---------------------------------------------------------------------------
__global__ __launch_bounds__(64)
void scan_pass1(const bf16_t* __restrict__ dt, const bf16_t* __restrict__ u,
                const float* __restrict__ x_dbl, const float* __restrict__ A_log,
                float* __restrict__ Pw, float* __restrict__ Sw) {
    int c = blockIdx.x;
    int d = blockIdx.y * 64 + threadIdx.x;
    int l0 = c * CHUNK;
    __shared__ float sB[CHUNK * NST];
    for (int i = threadIdx.x; i < CHUNK * NST; i += 64) {
        int l = i >> 4, n = i & 15;
        sB[i] = x_dbl[(size_t)(l0 + l) * XDBL_N + DTRANK + n];
    }
    __syncthreads();
    float Areg[NST], h[NST], P[NST];
#pragma unroll
    for (int n = 0; n < NST; n++) {
        Areg[n] = -__expf(A_log[d * NST + n]);
        h[n] = 0.f; P[n] = 1.f;
    }
    for (int l = 0; l < CHUNK; l++) {
        int gl = l0 + l;
        float dtl = __bfloat162float(dt[(size_t)gl * DI + d]);
        float ul  = __bfloat162float(u[(size_t)gl * DI + d]);
        float du = dtl * ul;
#pragma unroll
        for (int n = 0; n < NST; n++) {
            float a = __expf(dtl * Areg[n]);
            P[n] *= a;
            h[n] = a * h[n] + du * sB[l * NST + n];
        }
    }
    size_t base = (size_t)c * (DI * NST) + (size_t)d * NST;
#pragma unroll
    for (int n = 0; n < NST; n++) { Pw[base + n] = P[n]; Sw[base + n] = h[n]; }
}

// ---------------------------------------------------------------------------
// Selective scan pass 2: sequential prefix over chunks
// ---------------------------------------------------------------------------
__global__ __launch_bounds__(256)
void scan_pass2(const float* __restrict__ Pw, const float* __restrict__ Sw,
                float* __restrict__ initw) {
    int tid = blockIdx.x * 256 + threadIdx.x;   // 0 .. DI*NST-1
    if (tid >= DI * NST) return;
    float h = 0.f;
    for (int c = 0; c < NCHUNK; c++) {
        size_t idx = (size_t)c * (DI * NST) + tid;
        initw[idx] = h;
        h = Pw[idx] * h + Sw[idx];
    }
}

// ---------------------------------------------------------------------------
// Selective scan pass 3: replay with init, emit yy = (h.C + u*D) * silu(z)
// ---------------------------------------------------------------------------
__global__ __launch_bounds__(64)
void scan_pass3(const bf16_t* __restrict__ dt, const bf16_t* __restrict__ u,
                const float* __restrict__ x_dbl, const float* __restrict__ A_log,
                const float* __restrict__ Dp, const float* __restrict__ initw,
                const bf16_t* __restrict__ xz, bf16_t* __restrict__ yy) {
    int c = blockIdx.x;
    int d = blockIdx.y * 64 + threadIdx.x;
    int l0 = c * CHUNK;
    __shared__ float sBC[CHUNK * 2 * NST];
    for (int i = threadIdx.x; i < CHUNK * 2 * NST; i += 64) {
        int l = i >> 5, n = i & 31;
        sBC[i] = x_dbl[(size_t)(l0 + l) * XDBL_N + DTRANK + n];
    }
    __syncthreads();
    float Areg[NST], h[NST];
    size_t base = (size_t)c * (DI * NST) + (size_t)d * NST;
#pragma unroll
    for (int n = 0; n < NST; n++) {
        Areg[n] = -__expf(A_log[d * NST + n]);
        h[n] = initw[base + n];
    }
    float Dd = Dp[d];
    for (int l = 0; l < CHUNK; l++) {
        int gl = l0 + l;
        float dtl = __bfloat162float(dt[(size_t)gl * DI + d]);
        float ul  = __bfloat162float(u[(size_t)gl * DI + d]);
        float du = dtl * ul;
        float y = 0.f;
#pragma unroll
        for (int n = 0; n < NST; n++) {
            float a = __expf(dtl * Areg[n]);
            h[n] = a * h[n] + du * sBC[l * 32 + n];
            y += h[n] * sBC[l * 32 + NST + n];
        }
        float zv = __bfloat162float(xz[(size_t)gl * (2 * DI) + DI + d]);
        float sz = zv / (1.f + __expf(-zv));
        yy[(size_t)gl * DI + d] = __float2bfloat16((y + ul * Dd) * sz);
    }
}

// ---------------------------------------------------------------------------
// AvgPool3d (1,4,4) -> bf16
// ---------------------------------------------------------------------------
__global__ __launch_bounds__(256)
void avgpool_kernel(const float* __restrict__ xf, bf16_t* __restrict__ pooled) {
    int idx = blockIdx.x * 256 + threadIdx.x;   // over 256*1024
    if (idx >= POOLED_ROWS * DMODEL) return;
    int dcol = idx & (DMODEL - 1);
    int p = idx >> 10;
    int f  = p >> 4;
    int i4 = (p >> 2) & 3;
    int j4 = p & 3;
    float s = 0.f;
#pragma unroll
    for (int ii = 0; ii < 4; ii++)
#pragma unroll
        for (int jj = 0; jj < 4; jj++) {
            int row = f * 256 + (i4 * 4 + ii) * 16 + (j4 * 4 + jj);
            s += xf[(size_t)row * DMODEL + dcol];
        }
    pooled[idx] = __float2bfloat16(s * (1.f / 16.f));
}

// ---------------------------------------------------------------------------
extern "C" void kernel_launch(void* const* d_in, const int* in_sizes, int n_in,
                              void* d_out, int out_size, void* d_ws, size_t ws_size,
                              hipStream_t stream) {
    const float* vst        = (const float*)d_in[0];
    const float* ln_w       = (const float*)d_in[1];
    const float* ln_b       = (const float*)d_in[2];
    const float* in_proj_w  = (const float*)d_in[3];
    const float* conv_w     = (const float*)d_in[4];
    const float* conv_b     = (const float*)d_in[5];
    const float* x_proj_w   = (const float*)d_in[6];
    const float* dt_proj_w  = (const float*)d_in[7];
    const float* dt_proj_b  = (const float*)d_in[8];
    const float* A_log      = (const float*)d_in[9];
    const float* D_param    = (const float*)d_in[10];
    const float* out_proj_w = (const float*)d_in[11];
    const float* fln_w      = (const float*)d_in[12];
    const float* fln_b      = (const float*)d_in[13];
    const float* mlp_w1     = (const float*)d_in[14];
    const float* mlp_b1     = (const float*)d_in[15];
    const float* mlp_w2     = (const float*)d_in[16];
    const float* mlp_b2     = (const float*)d_in[17];
    float* out = (float*)d_out;

    // ---------------- workspace layout ----------------
    char* wsb = (char*)d_ws;
    size_t off = 0;
    auto alloc_bf = [&](size_t n) { bf16_t* p = (bf16_t*)(wsb + off); off += n * 2; return p; };
    auto alloc_f  = [&](size_t n) { float*  p = (float*)(wsb + off); off += n * 4; return p; };

    // bf16 transposed weights
    bf16_t* w1t  = alloc_bf((size_t)(2 * DI) * DMODEL);   // [4096,1024]
    bf16_t* xpt  = alloc_bf((size_t)128 * DI);            // [128,2048] (96 padded)
    bf16_t* dtpt = alloc_bf((size_t)DI * DTRANK);         // [2048,64]
    bf16_t* opt  = alloc_bf((size_t)DMODEL * DI);         // [1024,2048]
    bf16_t* m1t  = alloc_bf((size_t)HID * DMODEL);        // [4096,1024]
    bf16_t* m2t  = alloc_bf((size_t)HID * HID);           // [4096,4096]
    // activations
    bf16_t* xz_bf   = alloc_bf((size_t)L_SEQ * 2 * DI);   // 33.5 MB
    bf16_t* u_bf    = alloc_bf((size_t)L_SEQ * DI);       // 16.8 MB
    bf16_t* dt_bf   = alloc_bf((size_t)L_SEQ * DI);       // 16.8 MB
    bf16_t* xdbl_bf = alloc_bf((size_t)L_SEQ * XDBL_N);
    bf16_t* yy_bf   = alloc_bf((size_t)L_SEQ * DI);       // 16.8 MB
    float*  xdbl_f  = alloc_f((size_t)L_SEQ * XDBL_N);
    float*  Pw      = alloc_f((size_t)NCHUNK * DI * NST); // 8.4 MB
    float*  Sw      = alloc_f((size_t)NCHUNK * DI * NST); // 8.4 MB
    float*  initw   = alloc_f((size_t)NCHUNK * DI * NST); // 8.4 MB
    // aliases over dead regions
    bf16_t* xn_bf   = yy_bf;           // LN1 out; dead before pass3 writes yy
    float*  g2part  = Pw;              // [8][4096][128] fp32 = 16.8 MB, dead before pass1
    float*  x2_f    = Pw;              // [4096][1024] fp32, live after pass2
    float*  xf_f    = (float*)u_bf;    // u dead after pass3
    bf16_t* pooled  = dt_bf;           // dt dead after pass3
    bf16_t* h1_bf   = dt_bf + (size_t)POOLED_ROWS * DMODEL;
    float*  g5part  = (float*)yy_bf;   // [4][256][4096] fp32 = 16.8 MB, yy dead after G4
    float*  g6part  = (float*)xz_bf;   // [8][256][4096] fp32 = 33.5 MB, xz dead after pass3

    dim3 blk256(256);

    // 0) weight transpose+convert (fp32 [K,N] -> bf16 [Npad,K])
    transpose_bf16_kernel<<<dim3((2 * DI) / 32, DMODEL / 32), blk256, 0, stream>>>(
        in_proj_w, DMODEL, 2 * DI, 2 * DI, w1t);
    transpose_bf16_kernel<<<dim3(128 / 32, DI / 32), blk256, 0, stream>>>(
        x_proj_w, DI, XDBL_N, 128, xpt);
    transpose_bf16_kernel<<<dim3(DI / 32, DTRANK / 32), blk256, 0, stream>>>(
        dt_proj_w, DTRANK, DI, DI, dtpt);
    transpose_bf16_kernel<<<dim3(DMODEL / 32, DI / 32), blk256, 0, stream>>>(
        out_proj_w, DI, DMODEL, DMODEL, opt);
    transpose_bf16_kernel<<<dim3(HID / 32, DMODEL / 32), blk256, 0, stream>>>(
        mlp_w1, DMODEL, HID, HID, m1t);
    transpose_bf16_kernel<<<dim3(HID / 32, HID / 32), blk256, 0, stream>>>(
        mlp_w2, HID, HID, HID, m2t);

    // 1) LN1: vst -> xn_bf
    ln_kernel<true><<<L_SEQ, blk256, 0, stream>>>(vst, ln_w, ln_b, xn_bf);

    // 2) G1: xz = xn @ in_proj  -> bf16 [L,4096]
    mfma_gemm<0><<<dim3((2 * DI) / 128, L_SEQ / 128), blk256, 0, stream>>>(
        xn_bf, DMODEL, w1t, DMODEL, DMODEL, nullptr, xz_bf, 2 * DI, nullptr, nullptr);

    // 3) conv+silu: xz[:,:DI] -> u_bf
    conv_silu_kernel<<<(L_SEQ * DI) / 256, blk256, 0, stream>>>(xz_bf, conv_w, conv_b, u_bf);

    // 4) G2 split-K(8): x_dbl = u @ x_proj  [4096,2048]x[2048,96->128]
    mfma_gemm_splitk<<<dim3(1, L_SEQ / 128, 8), blk256, 0, stream>>>(
        u_bf, DI, xpt, DI, DI / 8, g2part, 128, (size_t)L_SEQ * 128);
    reduce_splitk<8, 0><<<(L_SEQ * XDBL_N) / 256, blk256, 0, stream>>>(
        g2part, (size_t)L_SEQ * 128, 128, L_SEQ, XDBL_N, xdbl_f, xdbl_bf, XDBL_N, nullptr);

    // 5) G3: dt = softplus(x_dbl[:,:64] @ dt_proj + b) -> bf16 [L,2048]
    mfma_gemm<1><<<dim3(DI / 128, L_SEQ / 128), blk256, 0, stream>>>(
        xdbl_bf, XDBL_N, dtpt, DTRANK, DTRANK, nullptr, dt_bf, DI, dt_proj_b, nullptr);

    // 6-8) chunked selective scan
    scan_pass1<<<dim3(NCHUNK, DI / 64), dim3(64), 0, stream>>>(
        dt_bf, u_bf, xdbl_f, A_log, Pw, Sw);
    scan_pass2<<<(DI * NST) / 256, blk256, 0, stream>>>(Pw, Sw, initw);
    scan_pass3<<<dim3(NCHUNK, DI / 64), dim3(64), 0, stream>>>(
        dt_bf, u_bf, xdbl_f, A_log, D_param, initw, xz_bf, yy_bf);

    // 9) G4: x2 = vst + yy @ out_proj -> fp32 [L,1024]
    mfma_gemm<2><<<dim3(DMODEL / 128, L_SEQ / 128), blk256, 0, stream>>>(
        yy_bf, DI, opt, DI, DI, x2_f, nullptr, DMODEL, nullptr, vst);

    // 10) LN2: x2 -> xf (fp32)
    ln_kernel<false><<<L_SEQ, blk256, 0, stream>>>(x2_f, fln_w, fln_b, xf_f);

    // 11) avgpool: xf -> pooled bf16 [256,1024]
    avgpool_kernel<<<(POOLED_ROWS * DMODEL) / 256, blk256, 0, stream>>>(xf_f, pooled);

    // 12) G5 split-K(4): h1 = gelu(pooled @ mlp_w1 + b1) -> bf16 [256,4096]
    mfma_gemm_splitk<<<dim3(HID / 128, POOLED_ROWS / 128, 4), blk256, 0, stream>>>(
        pooled, DMODEL, m1t, DMODEL, DMODEL / 4, g5part, HID, (size_t)POOLED_ROWS * HID);
    reduce_splitk<4, 1><<<(POOLED_ROWS * HID) / 256, blk256, 0, stream>>>(
        g5part, (size_t)POOLED_ROWS * HID, HID, POOLED_ROWS, HID, nullptr, h1_bf, HID, mlp_b1);

    // 13) G6 split-K(8): out = h1 @ mlp_w2 + b2 -> fp32 [256,4096]
    mfma_gemm_splitk<<<dim3(HID / 128, POOLED_ROWS / 128, 8), blk256, 0, stream>>>(
        h1_bf, HID, m2t, HID, HID / 8, g6part, HID, (size_t)POOLED_ROWS * HID);
    reduce_splitk<8, 2><<<(POOLED_ROWS * HID) / 256, blk256, 0, stream>>>(
        g6part, (size_t)POOLED_ROWS * HID, HID, POOLED_ROWS, HID, out, nullptr, HID, mlp_b2);
}

// Round 4
// 519.033 us; speedup vs baseline: 5.5512x; 1.0157x over previous
//
#include <hip/hip_runtime.h>
#include <hip/hip_bf16.h>
#include <math.h>

typedef __hip_bfloat16 bf16_t;
typedef __attribute__((ext_vector_type(8))) short short8;
typedef __attribute__((ext_vector_type(4))) float f32x4;

// Problem constants
#define L_SEQ   4096      // F*P = 16*256
#define DMODEL  1024
#define DI      2048
#define NST     16
#define DTRANK  64
#define XDBL_N  96        // DTRANK + 2*NST
#define HID     4096
#define CHUNK   32
#define NCHUNK  128       // L_SEQ / CHUNK
#define POOLED_ROWS 256   // 16 frames * 4 * 4

// ---------------------------------------------------------------------------
// async global->LDS 16B copy (global_load_lds_dwordx4)
// ---------------------------------------------------------------------------
__device__ __forceinline__ void async_load16(const bf16_t* g, bf16_t* l) {
    __builtin_amdgcn_global_load_lds(
        (const __attribute__((address_space(1))) void*)g,
        (__attribute__((address_space(3))) void*)l,
        16, 0, 0);
}

// ---------------------------------------------------------------------------
// Transpose+convert: in fp32 [K,N] row-major -> out bf16 [Npad,K] row-major.
// ---------------------------------------------------------------------------
__global__ __launch_bounds__(256)
void transpose_bf16_kernel(const float* __restrict__ in, int K, int N, int Npad,
                           bf16_t* __restrict__ out) {
    __shared__ float t[32][33];
    int k0 = blockIdx.y * 32, n0 = blockIdx.x * 32;
    int tx = threadIdx.x & 31, ty = threadIdx.x >> 5;   // ty in 0..7
#pragma unroll
    for (int i = 0; i < 4; i++) {
        int k = k0 + ty + i * 8, n = n0 + tx;
        t[ty + i * 8][tx] = (n < N) ? in[(size_t)k * N + n] : 0.f;
    }
    __syncthreads();
#pragma unroll
    for (int i = 0; i < 4; i++) {
        int n = n0 + ty + i * 8, k = k0 + tx;
        if (n < Npad) out[(size_t)n * K + k] = __float2bfloat16(t[tx][ty + i * 8]);
    }
}

// ---------------------------------------------------------------------------
// LayerNorm: one block per row, 1024 cols; templated output dtype
// ---------------------------------------------------------------------------
template <bool BF16OUT>
__global__ __launch_bounds__(256)
void ln_kernel(const float* __restrict__ x, const float* __restrict__ w,
               const float* __restrict__ b, void* __restrict__ out_) {
    int row = blockIdx.x;
    int tid = threadIdx.x;
    const float* xr = x + (size_t)row * DMODEL;
    float v[4];
    float s = 0.f, ss = 0.f;
#pragma unroll
    for (int e = 0; e < 4; e++) {
        v[e] = xr[tid + e * 256];
        s += v[e];
        ss += v[e] * v[e];
    }
#pragma unroll
    for (int off = 32; off > 0; off >>= 1) {
        s  += __shfl_down(s, off);
        ss += __shfl_down(ss, off);
    }
    __shared__ float rs[4], rss[4];
    int wid = tid >> 6;
    if ((tid & 63) == 0) { rs[wid] = s; rss[wid] = ss; }
    __syncthreads();
    s  = rs[0] + rs[1] + rs[2] + rs[3];
    ss = rss[0] + rss[1] + rss[2] + rss[3];
    float mu  = s * (1.f / DMODEL);
    float var = ss * (1.f / DMODEL) - mu * mu;
    float inv = rsqrtf(var + 1e-5f);
#pragma unroll
    for (int e = 0; e < 4; e++) {
        int col = tid + e * 256;
        float o = (v[e] - mu) * inv * w[col] + b[col];
        if (BF16OUT) ((bf16_t*)out_)[(size_t)row * DMODEL + col] = __float2bfloat16(o);
        else         ((float*)out_)[(size_t)row * DMODEL + col] = o;
    }
}

// ---------------------------------------------------------------------------
// bf16 MFMA GEMM: C[M,Nt] = epi(A[M,K] @ Bt[Nt,K]^T)
// 128x128 tile, BK=32, 256 threads (4 waves), each wave 64x64 via 4x4 MFMAs.
// EPI: 0 = store bf16; 1 = bias+softplus -> bf16; 2 = +res(fp32) -> fp32
// ---------------------------------------------------------------------------
template <int EPI>
__global__ __launch_bounds__(256, 2)
void mfma_gemm(const bf16_t* __restrict__ A, int lda,
               const bf16_t* __restrict__ Bt, int ldb,
               int K,
               float* __restrict__ Cf, bf16_t* __restrict__ Cb, int ldc,
               const float* __restrict__ bias, const float* __restrict__ res) {
    __shared__ bf16_t Asl[128 * 32];
    __shared__ bf16_t Bsl[128 * 32];
    const int tid = threadIdx.x;
    const int l = tid & 63, w = tid >> 6;
    const int m0 = blockIdx.y * 128, n0 = blockIdx.x * 128;
    const int wm = (w >> 1) * 64, wn = (w & 1) * 64;

    const int srow = tid >> 2;
    const int skc = (tid & 3) * 8;
    const bf16_t* Ag = A + (size_t)(m0 + srow) * lda + skc;
    const bf16_t* Bg = Bt + (size_t)(n0 + srow) * ldb + skc;
    bf16_t* As0 = Asl + (size_t)(w * 64) * 8;
    bf16_t* As1 = Asl + (size_t)(256 + w * 64) * 8;
    bf16_t* Bs0 = Bsl + (size_t)(w * 64) * 8;
    bf16_t* Bs1 = Bsl + (size_t)(256 + w * 64) * 8;

    f32x4 acc[4][4];
#pragma unroll
    for (int i = 0; i < 4; i++)
#pragma unroll
        for (int j = 0; j < 4; j++) acc[i][j] = (f32x4){0.f, 0.f, 0.f, 0.f};

    const short8* Asv = (const short8*)Asl;
    const short8* Bsv = (const short8*)Bsl;
    const int fr = l >> 4;
    const int fc = l & 15;

    for (int k0 = 0; k0 < K; k0 += 32) {
        __syncthreads();
        async_load16(Ag, As0);
        async_load16(Ag + (size_t)64 * lda, As1);
        async_load16(Bg, Bs0);
        async_load16(Bg + (size_t)64 * ldb, Bs1);
        Ag += 32; Bg += 32;
        __syncthreads();

        short8 a[4], b[4];
#pragma unroll
        for (int im = 0; im < 4; im++)
            a[im] = Asv[(wm + im * 16 + fc) * 4 + fr];
#pragma unroll
        for (int in = 0; in < 4; in++)
            b[in] = Bsv[(wn + in * 16 + fc) * 4 + fr];
#pragma unroll
        for (int im = 0; im < 4; im++)
#pragma unroll
            for (int in = 0; in < 4; in++)
                acc[im][in] = __builtin_amdgcn_mfma_f32_16x16x32_bf16(
                    a[im], b[in], acc[im][in], 0, 0, 0);
    }

    // Epilogue: D[row][col]: col = lane&15, row = (lane>>4)*4 + reg
#pragma unroll
    for (int im = 0; im < 4; im++) {
        int mbase = m0 + wm + im * 16 + fr * 4;
#pragma unroll
        for (int in = 0; in < 4; in++) {
            int n = n0 + wn + in * 16 + fc;
            float bv = (EPI == 1) ? bias[n] : 0.f;
#pragma unroll
            for (int v = 0; v < 4; v++) {
                float x = acc[im][in][v];
                size_t off = (size_t)(mbase + v) * ldc + n;
                if (EPI == 0) {
                    Cb[off] = __float2bfloat16(x);
                } else if (EPI == 1) {
                    x += bv;
                    x = (x > 20.f) ? x : log1pf(__expf(x));
                    Cb[off] = __float2bfloat16(x);
                } else if (EPI == 2) {
                    Cf[off] = x + res[off];
                }
            }
        }
    }
}

// ---------------------------------------------------------------------------
// Split-K variant: grid.z = K-split; stores fp32 partials, no epilogue.
// ---------------------------------------------------------------------------
__global__ __launch_bounds__(256, 2)
void mfma_gemm_splitk(const bf16_t* __restrict__ A, int lda,
                      const bf16_t* __restrict__ Bt, int ldb,
                      int Kper, float* __restrict__ Cpart, int ldc,
                      size_t pstride) {
    __shared__ bf16_t Asl[128 * 32];
    __shared__ bf16_t Bsl[128 * 32];
    const int tid = threadIdx.x;
    const int l = tid & 63, w = tid >> 6;
    const int m0 = blockIdx.y * 128, n0 = blockIdx.x * 128;
    const int wm = (w >> 1) * 64, wn = (w & 1) * 64;
    const int kbase = blockIdx.z * Kper;

    const int srow = tid >> 2;
    const int skc = (tid & 3) * 8;
    const bf16_t* Ag = A + (size_t)(m0 + srow) * lda + kbase + skc;
    const bf16_t* Bg = Bt + (size_t)(n0 + srow) * ldb + kbase + skc;
    bf16_t* As0 = Asl + (size_t)(w * 64) * 8;
    bf16_t* As1 = Asl + (size_t)(256 + w * 64) * 8;
    bf16_t* Bs0 = Bsl + (size_t)(w * 64) * 8;
    bf16_t* Bs1 = Bsl + (size_t)(256 + w * 64) * 8;

    f32x4 acc[4][4];
#pragma unroll
    for (int i = 0; i < 4; i++)
#pragma unroll
        for (int j = 0; j < 4; j++) acc[i][j] = (f32x4){0.f, 0.f, 0.f, 0.f};

    const short8* Asv = (const short8*)Asl;
    const short8* Bsv = (const short8*)Bsl;
    const int fr = l >> 4;
    const int fc = l & 15;

    for (int k0 = 0; k0 < Kper; k0 += 32) {
        __syncthreads();
        async_load16(Ag, As0);
        async_load16(Ag + (size_t)64 * lda, As1);
        async_load16(Bg, Bs0);
        async_load16(Bg + (size_t)64 * ldb, Bs1);
        Ag += 32; Bg += 32;
        __syncthreads();

        short8 a[4], b[4];
#pragma unroll
        for (int im = 0; im < 4; im++)
            a[im] = Asv[(wm + im * 16 + fc) * 4 + fr];
#pragma unroll
        for (int in = 0; in < 4; in++)
            b[in] = Bsv[(wn + in * 16 + fc) * 4 + fr];
#pragma unroll
        for (int im = 0; im < 4; im++)
#pragma unroll
            for (int in = 0; in < 4; in++)
                acc[im][in] = __builtin_amdgcn_mfma_f32_16x16x32_bf16(
                    a[im], b[in], acc[im][in], 0, 0, 0);
    }

    float* Cz = Cpart + (size_t)blockIdx.z * pstride;
#pragma unroll
    for (int im = 0; im < 4; im++) {
        int mbase = m0 + wm + im * 16 + fr * 4;
#pragma unroll
        for (int in = 0; in < 4; in++) {
            int n = n0 + wn + in * 16 + fc;
#pragma unroll
            for (int v = 0; v < 4; v++)
                Cz[(size_t)(mbase + v) * ldc + n] = acc[im][in][v];
        }
    }
}

// ---------------------------------------------------------------------------
// Split-K reduce. EPI: 0 = store fp32+bf16; 1 = bias+gelu -> bf16; 2 = bias -> fp32
// ---------------------------------------------------------------------------
template <int S, int EPI>
__global__ __launch_bounds__(256)
void reduce_splitk(const float* __restrict__ part, size_t pstride, int ldp,
                   int M, int N, float* __restrict__ outf, bf16_t* __restrict__ outb,
                   int ldo, const float* __restrict__ bias) {
    int idx = blockIdx.x * 256 + threadIdx.x;
    if (idx >= M * N) return;
    int r = idx / N, c = idx - r * N;
    float s = 0.f;
#pragma unroll
    for (int z = 0; z < S; z++)
        s += part[(size_t)z * pstride + (size_t)r * ldp + c];
    size_t o = (size_t)r * ldo + c;
    if (EPI == 0) {
        outf[o] = s;
        outb[o] = __float2bfloat16(s);
    } else if (EPI == 1) {
        s += bias[c];
        s = 0.5f * s * (1.f + erff(s * 0.70710678118654752f));
        outb[o] = __float2bfloat16(s);
    } else {
        outf[o] = s + bias[c];
    }
}

// ---------------------------------------------------------------------------
// Depthwise causal conv (k=4) + bias + silu. xin = xz[:, 0:DI] (bf16, ld 2*DI)
// ---------------------------------------------------------------------------
__global__ __launch_bounds__(256)
void conv_silu_kernel(const bf16_t* __restrict__ xz, const float* __restrict__ cw,
                      const float* __restrict__ cb, bf16_t* __restrict__ u) {
    int idx = blockIdx.x * 256 + threadIdx.x;      // over L_SEQ*DI
    if (idx >= L_SEQ * DI) return;
    int ch = idx & (DI - 1);
    int l  = idx >> 11;
    float acc = cb[ch];
#pragma unroll
    for (int k = 0; k < 4; k++) {
        int ls = l - 3 + k;
        if (ls >= 0)
            acc += cw[ch * 4 + k] * __bfloat162float(xz[(size_t)ls * (2 * DI) + ch]);
    }
    u[idx] = __float2bfloat16(acc / (1.f + __expf(-acc)));
}

// ---------------------------------------------------------------------------
// Selective scan pass 1: per chunk/d: P[n]=exp(A[n]*sum dt), S[n]=state from 0.
// Register-prefetched dt/u; 16 exps/step for the decay only.
// ---------------------------------------------------------------------------
__global__ __launch_bounds__(64)
void scan_pass1(const bf16_t* __restrict__ dt, const bf16_t* __restrict__ u,
                const float* __restrict__ x_dbl, const float* __restrict__ A_log,
                float* __restrict__ Pw, float* __restrict__ Sw) {
    int c = blockIdx.x;
    int d = blockIdx.y * 64 + threadIdx.x;
    int l0 = c * CHUNK;
    __shared__ float sB[CHUNK * NST];
    for (int i = threadIdx.x; i < CHUNK * NST; i += 64) {
        int l = i >> 4, n = i & 15;
        sB[i] = x_dbl[(size_t)(l0 + l) * XDBL_N + DTRANK + n];
    }
    __syncthreads();
    float Areg[NST], h[NST];
#pragma unroll
    for (int n = 0; n < NST; n++) {
        Areg[n] = -__expf(A_log[d * NST + n]);
        h[n] = 0.f;
    }
    float dts = 0.f;
    float dtl = __bfloat162float(dt[(size_t)l0 * DI + d]);
    float ul  = __bfloat162float(u[(size_t)l0 * DI + d]);
    for (int l = 0; l < CHUNK; l++) {
        float dtn = 0.f, un = 0.f;
        if (l + 1 < CHUNK) {
            int gl = l0 + l + 1;
            dtn = __bfloat162float(dt[(size_t)gl * DI + d]);
            un  = __bfloat162float(u[(size_t)gl * DI + d]);
        }
        float du = dtl * ul;
        dts += dtl;
#pragma unroll
        for (int n = 0; n < NST; n++) {
            float a = __expf(dtl * Areg[n]);
            h[n] = a * h[n] + du * sB[l * NST + n];
        }
        dtl = dtn; ul = un;
    }
    size_t base = (size_t)c * (DI * NST) + (size_t)d * NST;
#pragma unroll
    for (int n = 0; n < NST; n++) {
        Pw[base + n] = __expf(dts * Areg[n]);
        Sw[base + n] = h[n];
    }
}

// ---------------------------------------------------------------------------
// Selective scan pass 2: sequential prefix over chunks; initw written in-place
// over Sw (read-before-write per element).
// ---------------------------------------------------------------------------
__global__ __launch_bounds__(256)
void scan_pass2(const float* __restrict__ Pw, float* __restrict__ SwInit) {
    int tid = blockIdx.x * 256 + threadIdx.x;   // 0 .. DI*NST-1
    if (tid >= DI * NST) return;
    float h = 0.f;
    for (int c = 0; c < NCHUNK; c++) {
        size_t idx = (size_t)c * (DI * NST) + tid;
        float s = SwInit[idx];
        SwInit[idx] = h;                 // becomes init state for chunk c
        h = Pw[idx] * h + s;
    }
}

// ---------------------------------------------------------------------------
// Selective scan pass 3: replay with init, emit yy = (h.C + u*D) * silu(z)
// Register-prefetched dt/u/z.
// ---------------------------------------------------------------------------
__global__ __launch_bounds__(64)
void scan_pass3(const bf16_t* __restrict__ dt, const bf16_t* __restrict__ u,
                const float* __restrict__ x_dbl, const float* __restrict__ A_log,
                const float* __restrict__ Dp, const float* __restrict__ initw,
                const bf16_t* __restrict__ xz, bf16_t* __restrict__ yy) {
    int c = blockIdx.x;
    int d = blockIdx.y * 64 + threadIdx.x;
    int l0 = c * CHUNK;
    __shared__ float sBC[CHUNK * 2 * NST];
    for (int i = threadIdx.x; i < CHUNK * 2 * NST; i += 64) {
        int l = i >> 5, n = i & 31;
        sBC[i] = x_dbl[(size_t)(l0 + l) * XDBL_N + DTRANK + n];
    }
    __syncthreads();
    float Areg[NST], h[NST];
    size_t base = (size_t)c * (DI * NST) + (size_t)d * NST;
#pragma unroll
    for (int n = 0; n < NST; n++) {
        Areg[n] = -__expf(A_log[d * NST + n]);
        h[n] = initw[base + n];
    }
    float Dd = Dp[d];
    float dtl = __bfloat162float(dt[(size_t)l0 * DI + d]);
    float ul  = __bfloat162float(u[(size_t)l0 * DI + d]);
    float zv  = __bfloat162float(xz[(size_t)l0 * (2 * DI) + DI + d]);
    for (int l = 0; l < CHUNK; l++) {
        float dtn = 0.f, un = 0.f, zn = 0.f;
        if (l + 1 < CHUNK) {
            int gl = l0 + l + 1;
            dtn = __bfloat162float(dt[(size_t)gl * DI + d]);
            un  = __bfloat162float(u[(size_t)gl * DI + d]);
            zn  = __bfloat162float(xz[(size_t)gl * (2 * DI) + DI + d]);
        }
        float du = dtl * ul;
        float y = 0.f;
#pragma unroll
        for (int n = 0; n < NST; n++) {
            float a = __expf(dtl * Areg[n]);
            h[n] = a * h[n] + du * sBC[l * 32 + n];
            y += h[n] * sBC[l * 32 + NST + n];
        }
        float sz = zv / (1.f + __expf(-zv));
        yy[(size_t)(l0 + l) * DI + d] = __float2bfloat16((y + ul * Dd) * sz);
        dtl = dtn; ul = un; zv = zn;
    }
}

// ---------------------------------------------------------------------------
// AvgPool3d (1,4,4) -> bf16
// ---------------------------------------------------------------------------
__global__ __launch_bounds__(256)
void avgpool_kernel(const float* __restrict__ xf, bf16_t* __restrict__ pooled) {
    int idx = blockIdx.x * 256 + threadIdx.x;   // over 256*1024
    if (idx >= POOLED_ROWS * DMODEL) return;
    int dcol = idx & (DMODEL - 1);
    int p = idx >> 10;
    int f  = p >> 4;
    int i4 = (p >> 2) & 3;
    int j4 = p & 3;
    float s = 0.f;
#pragma unroll
    for (int ii = 0; ii < 4; ii++)
#pragma unroll
        for (int jj = 0; jj < 4; jj++) {
            int row = f * 256 + (i4 * 4 + ii) * 16 + (j4 * 4 + jj);
            s += xf[(size_t)row * DMODEL + dcol];
        }
    pooled[idx] = __float2bfloat16(s * (1.f / 16.f));
}

// ---------------------------------------------------------------------------
extern "C" void kernel_launch(void* const* d_in, const int* in_sizes, int n_in,
                              void* d_out, int out_size, void* d_ws, size_t ws_size,
                              hipStream_t stream) {
    const float* vst        = (const float*)d_in[0];
    const float* ln_w       = (const float*)d_in[1];
    const float* ln_b       = (const float*)d_in[2];
    const float* in_proj_w  = (const float*)d_in[3];
    const float* conv_w     = (const float*)d_in[4];
    const float* conv_b     = (const float*)d_in[5];
    const float* x_proj_w   = (const float*)d_in[6];
    const float* dt_proj_w  = (const float*)d_in[7];
    const float* dt_proj_b  = (const float*)d_in[8];
    const float* A_log      = (const float*)d_in[9];
    const float* D_param    = (const float*)d_in[10];
    const float* out_proj_w = (const float*)d_in[11];
    const float* fln_w      = (const float*)d_in[12];
    const float* fln_b      = (const float*)d_in[13];
    const float* mlp_w1     = (const float*)d_in[14];
    const float* mlp_b1     = (const float*)d_in[15];
    const float* mlp_w2     = (const float*)d_in[16];
    const float* mlp_b2     = (const float*)d_in[17];
    float* out = (float*)d_out;

    // ---------------- workspace layout ----------------
    char* wsb = (char*)d_ws;
    size_t off = 0;
    auto alloc_bf = [&](size_t n) { bf16_t* p = (bf16_t*)(wsb + off); off += n * 2; return p; };
    auto alloc_f  = [&](size_t n) { float*  p = (float*)(wsb + off); off += n * 4; return p; };

    // bf16 transposed weights
    bf16_t* w1t  = alloc_bf((size_t)(2 * DI) * DMODEL);   // [4096,1024]
    bf16_t* xpt  = alloc_bf((size_t)128 * DI);            // [128,2048] (96 padded)
    bf16_t* dtpt = alloc_bf((size_t)DI * DTRANK);         // [2048,64]
    bf16_t* opt  = alloc_bf((size_t)DMODEL * DI);         // [1024,2048]
    bf16_t* m1t  = alloc_bf((size_t)HID * DMODEL);        // [4096,1024]
    bf16_t* m2t  = alloc_bf((size_t)HID * HID);           // [4096,4096]
    // activations
    bf16_t* xz_bf   = alloc_bf((size_t)L_SEQ * 2 * DI);   // 33.5 MB
    bf16_t* u_bf    = alloc_bf((size_t)L_SEQ * DI);       // 16.8 MB
    bf16_t* dt_bf   = alloc_bf((size_t)L_SEQ * DI);       // 16.8 MB
    bf16_t* xdbl_bf = alloc_bf((size_t)L_SEQ * XDBL_N);
    bf16_t* yy_bf   = alloc_bf((size_t)L_SEQ * DI);       // 16.8 MB
    float*  xdbl_f  = alloc_f((size_t)L_SEQ * XDBL_N);
    float*  Pw      = alloc_f((size_t)NCHUNK * DI * NST); // 16.8 MB
    float*  Sw      = alloc_f((size_t)NCHUNK * DI * NST); // 16.8 MB (also initw, in-place)
    // aliases over dead regions
    bf16_t* xn_bf   = yy_bf;           // LN1 out; dead before pass3 writes yy
    float*  g2part  = Pw;              // [8][4096][128] fp32 = 16.8 MB, dead before pass1
    float*  x2_f    = Pw;              // [4096][1024] fp32, live after pass2
    float*  xf_f    = (float*)u_bf;    // u dead after pass3
    bf16_t* pooled  = dt_bf;           // dt dead after pass3
    bf16_t* h1_bf   = dt_bf + (size_t)POOLED_ROWS * DMODEL;
    float*  g5part  = (float*)yy_bf;   // [4][256][4096] fp32 = 16.8 MB, yy dead after G4
    float*  g6part  = (float*)xz_bf;   // [8][256][4096] fp32 = 33.5 MB, xz dead after pass3

    dim3 blk256(256);

    // 0) weight transpose+convert (fp32 [K,N] -> bf16 [Npad,K])
    transpose_bf16_kernel<<<dim3((2 * DI) / 32, DMODEL / 32), blk256, 0, stream>>>(
        in_proj_w, DMODEL, 2 * DI, 2 * DI, w1t);
    transpose_bf16_kernel<<<dim3(128 / 32, DI / 32), blk256, 0, stream>>>(
        x_proj_w, DI, XDBL_N, 128, xpt);
    transpose_bf16_kernel<<<dim3(DI / 32, DTRANK / 32), blk256, 0, stream>>>(
        dt_proj_w, DTRANK, DI, DI, dtpt);
    transpose_bf16_kernel<<<dim3(DMODEL / 32, DI / 32), blk256, 0, stream>>>(
        out_proj_w, DI, DMODEL, DMODEL, opt);
    transpose_bf16_kernel<<<dim3(HID / 32, DMODEL / 32), blk256, 0, stream>>>(
        mlp_w1, DMODEL, HID, HID, m1t);
    transpose_bf16_kernel<<<dim3(HID / 32, HID / 32), blk256, 0, stream>>>(
        mlp_w2, HID, HID, HID, m2t);

    // 1) LN1: vst -> xn_bf
    ln_kernel<true><<<L_SEQ, blk256, 0, stream>>>(vst, ln_w, ln_b, xn_bf);

    // 2) G1: xz = xn @ in_proj  -> bf16 [L,4096]
    mfma_gemm<0><<<dim3((2 * DI) / 128, L_SEQ / 128), blk256, 0, stream>>>(
        xn_bf, DMODEL, w1t, DMODEL, DMODEL, nullptr, xz_bf, 2 * DI, nullptr, nullptr);

    // 3) conv+silu: xz[:,:DI] -> u_bf
    conv_silu_kernel<<<(L_SEQ * DI) / 256, blk256, 0, stream>>>(xz_bf, conv_w, conv_b, u_bf);

    // 4) G2 split-K(8): x_dbl = u @ x_proj  [4096,2048]x[2048,96->128]
    mfma_gemm_splitk<<<dim3(1, L_SEQ / 128, 8), blk256, 0, stream>>>(
        u_bf, DI, xpt, DI, DI / 8, g2part, 128, (size_t)L_SEQ * 128);
    reduce_splitk<8, 0><<<(L_SEQ * XDBL_N) / 256, blk256, 0, stream>>>(
        g2part, (size_t)L_SEQ * 128, 128, L_SEQ, XDBL_N, xdbl_f, xdbl_bf, XDBL_N, nullptr);

    // 5) G3: dt = softplus(x_dbl[:,:64] @ dt_proj + b) -> bf16 [L,2048]
    mfma_gemm<1><<<dim3(DI / 128, L_SEQ / 128), blk256, 0, stream>>>(
        xdbl_bf, XDBL_N, dtpt, DTRANK, DTRANK, nullptr, dt_bf, DI, dt_proj_b, nullptr);

    // 6-8) chunked selective scan (CHUNK=32, NCHUNK=128)
    scan_pass1<<<dim3(NCHUNK, DI / 64), dim3(64), 0, stream>>>(
        dt_bf, u_bf, xdbl_f, A_log, Pw, Sw);
    scan_pass2<<<(DI * NST) / 256, blk256, 0, stream>>>(Pw, Sw);
    scan_pass3<<<dim3(NCHUNK, DI / 64), dim3(64), 0, stream>>>(
        dt_bf, u_bf, xdbl_f, A_log, D_param, Sw, xz_bf, yy_bf);

    // 9) G4: x2 = vst + yy @ out_proj -> fp32 [L,1024]
    mfma_gemm<2><<<dim3(DMODEL / 128, L_SEQ / 128), blk256, 0, stream>>>(
        yy_bf, DI, opt, DI, DI, x2_f, nullptr, DMODEL, nullptr, vst);

    // 10) LN2: x2 -> xf (fp32)
    ln_kernel<false><<<L_SEQ, blk256, 0, stream>>>(x2_f, fln_w, fln_b, xf_f);

    // 11) avgpool: xf -> pooled bf16 [256,1024]
    avgpool_kernel<<<(POOLED_ROWS * DMODEL) / 256, blk256, 0, stream>>>(xf_f, pooled);

    // 12) G5 split-K(4): h1 = gelu(pooled @ mlp_w1 + b1) -> bf16 [256,4096]
    mfma_gemm_splitk<<<dim3(HID / 128, POOLED_ROWS / 128, 4), blk256, 0, stream>>>(
        pooled, DMODEL, m1t, DMODEL, DMODEL / 4, g5part, HID, (size_t)POOLED_ROWS * HID);
    reduce_splitk<4, 1><<<(POOLED_ROWS * HID) / 256, blk256, 0, stream>>>(
        g5part, (size_t)POOLED_ROWS * HID, HID, POOLED_ROWS, HID, nullptr, h1_bf, HID, mlp_b1);

    // 13) G6 split-K(8): out = h1 @ mlp_w2 + b2 -> fp32 [256,4096]
    mfma_gemm_splitk<<<dim3(HID / 128, POOLED_ROWS / 128, 8), blk256, 0, stream>>>(
        h1_bf, HID, m2t, HID, HID / 8, g6part, HID, (size_t)POOLED_ROWS * HID);
    reduce_splitk<8, 2><<<(POOLED_ROWS * HID) / 256, blk256, 0, stream>>>(
        g6part, (size_t)POOLED_ROWS * HID, HID, POOLED_ROWS, HID, out, nullptr, HID, mlp_b2);
}

// Round 5
// 496.819 us; speedup vs baseline: 5.7994x; 1.0447x over previous
//
#include <hip/hip_runtime.h>
#include <hip/hip_bf16.h>
#include <math.h>

typedef __hip_bfloat16 bf16_t;
typedef __attribute__((ext_vector_type(8))) short short8;
typedef __attribute__((ext_vector_type(4))) float f32x4;

// Problem constants
#define L_SEQ   4096      // F*P = 16*256
#define DMODEL  1024
#define DI      2048
#define NST     16
#define DTRANK  64
#define XDBL_N  96        // DTRANK + 2*NST
#define HID     4096
#define CHUNK   32
#define NCHUNK  128       // L_SEQ / CHUNK
#define POOLED_ROWS 256   // 16 frames * 4 * 4

// ---------------------------------------------------------------------------
// async global->LDS 16B copy (global_load_lds_dwordx4)
// ---------------------------------------------------------------------------
__device__ __forceinline__ void async_load16(const bf16_t* g, bf16_t* l) {
    __builtin_amdgcn_global_load_lds(
        (const __attribute__((address_space(1))) void*)g,
        (__attribute__((address_space(3))) void*)l,
        16, 0, 0);
}

// ---------------------------------------------------------------------------
// Fused transpose+convert for all 6 weights, one dispatch.
// Each job: fp32 [K,N] row-major -> bf16 [Npad,K] row-major (pad rows zero).
// Block counts (32x32 tiles): see table in kernel_launch.
// ---------------------------------------------------------------------------
__global__ __launch_bounds__(256)
void transpose_all_kernel(const float* __restrict__ j0, bf16_t* __restrict__ o0,
                          const float* __restrict__ j1, bf16_t* __restrict__ o1,
                          const float* __restrict__ j2, bf16_t* __restrict__ o2,
                          const float* __restrict__ j3, bf16_t* __restrict__ o3,
                          const float* __restrict__ j4, bf16_t* __restrict__ o4,
                          const float* __restrict__ j5, bf16_t* __restrict__ o5) {
    int b = blockIdx.x;
    const float* in; bf16_t* out; int K, N, Npad, local;
    if (b < 4096)        { in = j0; out = o0; K = 1024; N = 4096; Npad = 4096; local = b; }
    else if (b < 4352)   { in = j1; out = o1; K = 2048; N = 96;   Npad = 128;  local = b - 4096; }
    else if (b < 4480)   { in = j2; out = o2; K = 64;   N = 2048; Npad = 2048; local = b - 4352; }
    else if (b < 6528)   { in = j3; out = o3; K = 2048; N = 1024; Npad = 1024; local = b - 4480; }
    else if (b < 10624)  { in = j4; out = o4; K = 1024; N = 4096; Npad = 4096; local = b - 6528; }
    else                 { in = j5; out = o5; K = 4096; N = 4096; Npad = 4096; local = b - 10624; }
    int nb = Npad / 32;
    int k0 = (local / nb) * 32, n0 = (local % nb) * 32;

    __shared__ float t[32][33];
    int tx = threadIdx.x & 31, ty = threadIdx.x >> 5;   // ty in 0..7
#pragma unroll
    for (int i = 0; i < 4; i++) {
        int k = k0 + ty + i * 8, n = n0 + tx;
        t[ty + i * 8][tx] = (n < N) ? in[(size_t)k * N + n] : 0.f;
    }
    __syncthreads();
#pragma unroll
    for (int i = 0; i < 4; i++) {
        int n = n0 + ty + i * 8, k = k0 + tx;
        if (n < Npad) out[(size_t)n * K + k] = __float2bfloat16(t[tx][ty + i * 8]);
    }
}

// ---------------------------------------------------------------------------
// LayerNorm: one block per row, 1024 cols -> bf16
// ---------------------------------------------------------------------------
__global__ __launch_bounds__(256)
void ln_kernel(const float* __restrict__ x, const float* __restrict__ w,
               const float* __restrict__ b, bf16_t* __restrict__ out) {
    int row = blockIdx.x;
    int tid = threadIdx.x;
    const float* xr = x + (size_t)row * DMODEL;
    float v[4];
    float s = 0.f, ss = 0.f;
#pragma unroll
    for (int e = 0; e < 4; e++) {
        v[e] = xr[tid + e * 256];
        s += v[e];
        ss += v[e] * v[e];
    }
#pragma unroll
    for (int off = 32; off > 0; off >>= 1) {
        s  += __shfl_down(s, off);
        ss += __shfl_down(ss, off);
    }
    __shared__ float rs[4], rss[4];
    int wid = tid >> 6;
    if ((tid & 63) == 0) { rs[wid] = s; rss[wid] = ss; }
    __syncthreads();
    s  = rs[0] + rs[1] + rs[2] + rs[3];
    ss = rss[0] + rss[1] + rss[2] + rss[3];
    float mu  = s * (1.f / DMODEL);
    float var = ss * (1.f / DMODEL) - mu * mu;
    float inv = rsqrtf(var + 1e-5f);
#pragma unroll
    for (int e = 0; e < 4; e++) {
        int col = tid + e * 256;
        out[(size_t)row * DMODEL + col] =
            __float2bfloat16((v[e] - mu) * inv * w[col] + b[col]);
    }
}

// ---------------------------------------------------------------------------
// Fused LN2 + AvgPool(1,4,4): block per pooled row; LN 16 source rows, avg.
// ---------------------------------------------------------------------------
__global__ __launch_bounds__(256)
void ln_pool_kernel(const float* __restrict__ x, const float* __restrict__ w,
                    const float* __restrict__ b, bf16_t* __restrict__ pooled) {
    int p = blockIdx.x;                  // 0..255
    int tid = threadIdx.x;
    int f = p >> 4, i4 = (p >> 2) & 3, j4 = p & 3;
    __shared__ float rs[4], rss[4];
    float acc[4] = {0.f, 0.f, 0.f, 0.f};
    float wv[4], bv[4];
#pragma unroll
    for (int e = 0; e < 4; e++) { wv[e] = w[tid + e * 256]; bv[e] = b[tid + e * 256]; }
    for (int r16 = 0; r16 < 16; r16++) {
        int ii = r16 >> 2, jj = r16 & 3;
        int row = f * 256 + (i4 * 4 + ii) * 16 + j4 * 4 + jj;
        const float* xr = x + (size_t)row * DMODEL;
        float v[4];
        float s = 0.f, ss = 0.f;
#pragma unroll
        for (int e = 0; e < 4; e++) {
            v[e] = xr[tid + e * 256];
            s += v[e];
            ss += v[e] * v[e];
        }
#pragma unroll
        for (int off = 32; off > 0; off >>= 1) {
            s  += __shfl_down(s, off);
            ss += __shfl_down(ss, off);
        }
        int wid = tid >> 6;
        if ((tid & 63) == 0) { rs[wid] = s; rss[wid] = ss; }
        __syncthreads();
        s  = rs[0] + rs[1] + rs[2] + rs[3];
        ss = rss[0] + rss[1] + rss[2] + rss[3];
        float mu  = s * (1.f / DMODEL);
        float var = ss * (1.f / DMODEL) - mu * mu;
        float inv = rsqrtf(var + 1e-5f);
#pragma unroll
        for (int e = 0; e < 4; e++)
            acc[e] += (v[e] - mu) * inv * wv[e] + bv[e];
        __syncthreads();
    }
#pragma unroll
    for (int e = 0; e < 4; e++)
        pooled[(size_t)p * DMODEL + tid + e * 256] = __float2bfloat16(acc[e] * (1.f / 16.f));
}

// ---------------------------------------------------------------------------
// bf16 MFMA GEMM: C[M,Nt] = epi(A[M,K] @ Bt[Nt,K]^T)
// 128x128 tile, BK=32, 256 threads (4 waves), each wave 64x64 via 4x4 MFMAs.
// EPI: 0 = store bf16; 1 = bias+softplus -> bf16
// ---------------------------------------------------------------------------
template <int EPI>
__global__ __launch_bounds__(256, 2)
void mfma_gemm(const bf16_t* __restrict__ A, int lda,
               const bf16_t* __restrict__ Bt, int ldb,
               int K,
               float* __restrict__ Cf, bf16_t* __restrict__ Cb, int ldc,
               const float* __restrict__ bias, const float* __restrict__ res) {
    __shared__ bf16_t Asl[128 * 32];
    __shared__ bf16_t Bsl[128 * 32];
    const int tid = threadIdx.x;
    const int l = tid & 63, w = tid >> 6;
    const int m0 = blockIdx.y * 128, n0 = blockIdx.x * 128;
    const int wm = (w >> 1) * 64, wn = (w & 1) * 64;

    const int srow = tid >> 2;
    const int skc = (tid & 3) * 8;
    const bf16_t* Ag = A + (size_t)(m0 + srow) * lda + skc;
    const bf16_t* Bg = Bt + (size_t)(n0 + srow) * ldb + skc;
    bf16_t* As0 = Asl + (size_t)(w * 64) * 8;
    bf16_t* As1 = Asl + (size_t)(256 + w * 64) * 8;
    bf16_t* Bs0 = Bsl + (size_t)(w * 64) * 8;
    bf16_t* Bs1 = Bsl + (size_t)(256 + w * 64) * 8;

    f32x4 acc[4][4];
#pragma unroll
    for (int i = 0; i < 4; i++)
#pragma unroll
        for (int j = 0; j < 4; j++) acc[i][j] = (f32x4){0.f, 0.f, 0.f, 0.f};

    const short8* Asv = (const short8*)Asl;
    const short8* Bsv = (const short8*)Bsl;
    const int fr = l >> 4;
    const int fc = l & 15;

    for (int k0 = 0; k0 < K; k0 += 32) {
        __syncthreads();
        async_load16(Ag, As0);
        async_load16(Ag + (size_t)64 * lda, As1);
        async_load16(Bg, Bs0);
        async_load16(Bg + (size_t)64 * ldb, Bs1);
        Ag += 32; Bg += 32;
        __syncthreads();

        short8 a[4], b[4];
#pragma unroll
        for (int im = 0; im < 4; im++)
            a[im] = Asv[(wm + im * 16 + fc) * 4 + fr];
#pragma unroll
        for (int in = 0; in < 4; in++)
            b[in] = Bsv[(wn + in * 16 + fc) * 4 + fr];
#pragma unroll
        for (int im = 0; im < 4; im++)
#pragma unroll
            for (int in = 0; in < 4; in++)
                acc[im][in] = __builtin_amdgcn_mfma_f32_16x16x32_bf16(
                    a[im], b[in], acc[im][in], 0, 0, 0);
    }

    // Epilogue: D[row][col]: col = lane&15, row = (lane>>4)*4 + reg
#pragma unroll
    for (int im = 0; im < 4; im++) {
        int mbase = m0 + wm + im * 16 + fr * 4;
#pragma unroll
        for (int in = 0; in < 4; in++) {
            int n = n0 + wn + in * 16 + fc;
            float bv = (EPI == 1) ? bias[n] : 0.f;
#pragma unroll
            for (int v = 0; v < 4; v++) {
                float x = acc[im][in][v];
                size_t off = (size_t)(mbase + v) * ldc + n;
                if (EPI == 0) {
                    Cb[off] = __float2bfloat16(x);
                } else if (EPI == 1) {
                    x += bv;
                    x = (x > 20.f) ? x : log1pf(__expf(x));
                    Cb[off] = __float2bfloat16(x);
                }
            }
        }
    }
}

// ---------------------------------------------------------------------------
// 64x128-tile GEMM with fp32 residual epilogue (for G4: M=4096, N=1024).
// 512 blocks -> 2 blocks/CU for wave-level overlap. 4 waves, each 64Mx32N.
// ---------------------------------------------------------------------------
__global__ __launch_bounds__(256, 2)
void mfma_gemm64_res(const bf16_t* __restrict__ A, int lda,
                     const bf16_t* __restrict__ Bt, int ldb,
                     int K, float* __restrict__ Cf, int ldc,
                     const float* __restrict__ res) {
    __shared__ bf16_t Asl[64 * 32];
    __shared__ bf16_t Bsl[128 * 32];
    const int tid = threadIdx.x;
    const int l = tid & 63, w = tid >> 6;
    const int m0 = blockIdx.y * 64, n0 = blockIdx.x * 128;
    const int wn = w * 32;

    const int srow = tid >> 2;
    const int skc = (tid & 3) * 8;
    const bf16_t* Ag = A + (size_t)(m0 + srow) * lda + skc;
    const bf16_t* Bg = Bt + (size_t)(n0 + srow) * ldb + skc;
    bf16_t* As0 = Asl + (size_t)(w * 64) * 8;
    bf16_t* Bs0 = Bsl + (size_t)(w * 64) * 8;
    bf16_t* Bs1 = Bsl + (size_t)(256 + w * 64) * 8;

    f32x4 acc[4][2];
#pragma unroll
    for (int i = 0; i < 4; i++)
#pragma unroll
        for (int j = 0; j < 2; j++) acc[i][j] = (f32x4){0.f, 0.f, 0.f, 0.f};

    const short8* Asv = (const short8*)Asl;
    const short8* Bsv = (const short8*)Bsl;
    const int fr = l >> 4;
    const int fc = l & 15;

    for (int k0 = 0; k0 < K; k0 += 32) {
        __syncthreads();
        async_load16(Ag, As0);
        async_load16(Bg, Bs0);
        async_load16(Bg + (size_t)64 * ldb, Bs1);
        Ag += 32; Bg += 32;
        __syncthreads();

        short8 a[4], b[2];
#pragma unroll
        for (int im = 0; im < 4; im++)
            a[im] = Asv[(im * 16 + fc) * 4 + fr];
#pragma unroll
        for (int in = 0; in < 2; in++)
            b[in] = Bsv[(wn + in * 16 + fc) * 4 + fr];
#pragma unroll
        for (int im = 0; im < 4; im++)
#pragma unroll
            for (int in = 0; in < 2; in++)
                acc[im][in] = __builtin_amdgcn_mfma_f32_16x16x32_bf16(
                    a[im], b[in], acc[im][in], 0, 0, 0);
    }

#pragma unroll
    for (int im = 0; im < 4; im++) {
        int mbase = m0 + im * 16 + fr * 4;
#pragma unroll
        for (int in = 0; in < 2; in++) {
            int n = n0 + wn + in * 16 + fc;
#pragma unroll
            for (int v = 0; v < 4; v++) {
                size_t off = (size_t)(mbase + v) * ldc + n;
                Cf[off] = acc[im][in][v] + res[off];
            }
        }
    }
}

// ---------------------------------------------------------------------------
// Split-K variant: grid.z = K-split; stores fp32 partials, no epilogue.
// ---------------------------------------------------------------------------
__global__ __launch_bounds__(256, 2)
void mfma_gemm_splitk(const bf16_t* __restrict__ A, int lda,
                      const bf16_t* __restrict__ Bt, int ldb,
                      int Kper, float* __restrict__ Cpart, int ldc,
                      size_t pstride) {
    __shared__ bf16_t Asl[128 * 32];
    __shared__ bf16_t Bsl[128 * 32];
    const int tid = threadIdx.x;
    const int l = tid & 63, w = tid >> 6;
    const int m0 = blockIdx.y * 128, n0 = blockIdx.x * 128;
    const int wm = (w >> 1) * 64, wn = (w & 1) * 64;
    const int kbase = blockIdx.z * Kper;

    const int srow = tid >> 2;
    const int skc = (tid & 3) * 8;
    const bf16_t* Ag = A + (size_t)(m0 + srow) * lda + kbase + skc;
    const bf16_t* Bg = Bt + (size_t)(n0 + srow) * ldb + kbase + skc;
    bf16_t* As0 = Asl + (size_t)(w * 64) * 8;
    bf16_t* As1 = Asl + (size_t)(256 + w * 64) * 8;
    bf16_t* Bs0 = Bsl + (size_t)(w * 64) * 8;
    bf16_t* Bs1 = Bsl + (size_t)(256 + w * 64) * 8;

    f32x4 acc[4][4];
#pragma unroll
    for (int i = 0; i < 4; i++)
#pragma unroll
        for (int j = 0; j < 4; j++) acc[i][j] = (f32x4){0.f, 0.f, 0.f, 0.f};

    const short8* Asv = (const short8*)Asl;
    const short8* Bsv = (const short8*)Bsl;
    const int fr = l >> 4;
    const int fc = l & 15;

    for (int k0 = 0; k0 < Kper; k0 += 32) {
        __syncthreads();
        async_load16(Ag, As0);
        async_load16(Ag + (size_t)64 * lda, As1);
        async_load16(Bg, Bs0);
        async_load16(Bg + (size_t)64 * ldb, Bs1);
        Ag += 32; Bg += 32;
        __syncthreads();

        short8 a[4], b[4];
#pragma unroll
        for (int im = 0; im < 4; im++)
            a[im] = Asv[(wm + im * 16 + fc) * 4 + fr];
#pragma unroll
        for (int in = 0; in < 4; in++)
            b[in] = Bsv[(wn + in * 16 + fc) * 4 + fr];
#pragma unroll
        for (int im = 0; im < 4; im++)
#pragma unroll
            for (int in = 0; in < 4; in++)
                acc[im][in] = __builtin_amdgcn_mfma_f32_16x16x32_bf16(
                    a[im], b[in], acc[im][in], 0, 0, 0);
    }

    float* Cz = Cpart + (size_t)blockIdx.z * pstride;
#pragma unroll
    for (int im = 0; im < 4; im++) {
        int mbase = m0 + wm + im * 16 + fr * 4;
#pragma unroll
        for (int in = 0; in < 4; in++) {
            int n = n0 + wn + in * 16 + fc;
#pragma unroll
            for (int v = 0; v < 4; v++)
                Cz[(size_t)(mbase + v) * ldc + n] = acc[im][in][v];
        }
    }
}

// ---------------------------------------------------------------------------
// Split-K reduce. EPI: 0 = store fp32+bf16; 1 = bias+gelu -> bf16; 2 = bias -> fp32
// ---------------------------------------------------------------------------
template <int S, int EPI>
__global__ __launch_bounds__(256)
void reduce_splitk(const float* __restrict__ part, size_t pstride, int ldp,
                   int M, int N, float* __restrict__ outf, bf16_t* __restrict__ outb,
                   int ldo, const float* __restrict__ bias) {
    int idx = blockIdx.x * 256 + threadIdx.x;
    if (idx >= M * N) return;
    int r = idx / N, c = idx - r * N;
    float s = 0.f;
#pragma unroll
    for (int z = 0; z < S; z++)
        s += part[(size_t)z * pstride + (size_t)r * ldp + c];
    size_t o = (size_t)r * ldo + c;
    if (EPI == 0) {
        outf[o] = s;
        outb[o] = __float2bfloat16(s);
    } else if (EPI == 1) {
        s += bias[c];
        s = 0.5f * s * (1.f + erff(s * 0.70710678118654752f));
        outb[o] = __float2bfloat16(s);
    } else {
        outf[o] = s + bias[c];
    }
}

// ---------------------------------------------------------------------------
// Depthwise causal conv (k=4) + bias + silu. xin = xz[:, 0:DI] (bf16, ld 2*DI)
// ---------------------------------------------------------------------------
__global__ __launch_bounds__(256)
void conv_silu_kernel(const bf16_t* __restrict__ xz, const float* __restrict__ cw,
                      const float* __restrict__ cb, bf16_t* __restrict__ u) {
    int idx = blockIdx.x * 256 + threadIdx.x;      // over L_SEQ*DI
    if (idx >= L_SEQ * DI) return;
    int ch = idx & (DI - 1);
    int l  = idx >> 11;
    float acc = cb[ch];
#pragma unroll
    for (int k = 0; k < 4; k++) {
        int ls = l - 3 + k;
        if (ls >= 0)
            acc += cw[ch * 4 + k] * __bfloat162float(xz[(size_t)ls * (2 * DI) + ch]);
    }
    u[idx] = __float2bfloat16(acc / (1.f + __expf(-acc)));
}

// ---------------------------------------------------------------------------
// Selective scan pass 1: per chunk/d: P[n]=exp(A[n]*sum dt), S[n]=state from 0.
// ---------------------------------------------------------------------------
__global__ __launch_bounds__(64)
void scan_pass1(const bf16_t* __restrict__ dt, const bf16_t* __restrict__ u,
                const float* __restrict__ x_dbl, const float* __restrict__ A_log,
                float* __restrict__ Pw, float* __restrict__ Sw) {
    int c = blockIdx.x;
    int d = blockIdx.y * 64 + threadIdx.x;
    int l0 = c * CHUNK;
    __shared__ float sB[CHUNK * NST];
    for (int i = threadIdx.x; i < CHUNK * NST; i += 64) {
        int l = i >> 4, n = i & 15;
        sB[i] = x_dbl[(size_t)(l0 + l) * XDBL_N + DTRANK + n];
    }
    __syncthreads();
    float Areg[NST], h[NST];
#pragma unroll
    for (int n = 0; n < NST; n++) {
        Areg[n] = -__expf(A_log[d * NST + n]);
        h[n] = 0.f;
    }
    float dts = 0.f;
    float dtl = __bfloat162float(dt[(size_t)l0 * DI + d]);
    float ul  = __bfloat162float(u[(size_t)l0 * DI + d]);
    for (int l = 0; l < CHUNK; l++) {
        float dtn = 0.f, un = 0.f;
        if (l + 1 < CHUNK) {
            int gl = l0 + l + 1;
            dtn = __bfloat162float(dt[(size_t)gl * DI + d]);
            un  = __bfloat162float(u[(size_t)gl * DI + d]);
        }
        float du = dtl * ul;
        dts += dtl;
#pragma unroll
        for (int n = 0; n < NST; n++) {
            float a = __expf(dtl * Areg[n]);
            h[n] = a * h[n] + du * sB[l * NST + n];
        }
        dtl = dtn; ul = un;
    }
    size_t base = (size_t)c * (DI * NST) + (size_t)d * NST;
#pragma unroll
    for (int n = 0; n < NST; n++) {
        Pw[base + n] = __expf(dts * Areg[n]);
        Sw[base + n] = h[n];
    }
}

// ---------------------------------------------------------------------------
// Selective scan pass 2: sequential prefix over chunks; init in-place over Sw.
// ---------------------------------------------------------------------------
__global__ __launch_bounds__(256)
void scan_pass2(const float* __restrict__ Pw, float* __restrict__ SwInit) {
    int tid = blockIdx.x * 256 + threadIdx.x;   // 0 .. DI*NST-1
    if (tid >= DI * NST) return;
    float h = 0.f;
    for (int c = 0; c < NCHUNK; c++) {
        size_t idx = (size_t)c * (DI * NST) + tid;
        float s = SwInit[idx];
        SwInit[idx] = h;                 // becomes init state for chunk c
        h = Pw[idx] * h + s;
    }
}

// ---------------------------------------------------------------------------
// Selective scan pass 3: replay with init, emit yy = (h.C + u*D) * silu(z)
// ---------------------------------------------------------------------------
__global__ __launch_bounds__(64)
void scan_pass3(const bf16_t* __restrict__ dt, const bf16_t* __restrict__ u,
                const float* __restrict__ x_dbl, const float* __restrict__ A_log,
                const float* __restrict__ Dp, const float* __restrict__ initw,
                const bf16_t* __restrict__ xz, bf16_t* __restrict__ yy) {
    int c = blockIdx.x;
    int d = blockIdx.y * 64 + threadIdx.x;
    int l0 = c * CHUNK;
    __shared__ float sBC[CHUNK * 2 * NST];
    for (int i = threadIdx.x; i < CHUNK * 2 * NST; i += 64) {
        int l = i >> 5, n = i & 31;
        sBC[i] = x_dbl[(size_t)(l0 + l) * XDBL_N + DTRANK + n];
    }
    __syncthreads();
    float Areg[NST], h[NST];
    size_t base = (size_t)c * (DI * NST) + (size_t)d * NST;
#pragma unroll
    for (int n = 0; n < NST; n++) {
        Areg[n] = -__expf(A_log[d * NST + n]);
        h[n] = initw[base + n];
    }
    float Dd = Dp[d];
    float dtl = __bfloat162float(dt[(size_t)l0 * DI + d]);
    float ul  = __bfloat162float(u[(size_t)l0 * DI + d]);
    float zv  = __bfloat162float(xz[(size_t)l0 * (2 * DI) + DI + d]);
    for (int l = 0; l < CHUNK; l++) {
        float dtn = 0.f, un = 0.f, zn = 0.f;
        if (l + 1 < CHUNK) {
            int gl = l0 + l + 1;
            dtn = __bfloat162float(dt[(size_t)gl * DI + d]);
            un  = __bfloat162float(u[(size_t)gl * DI + d]);
            zn  = __bfloat162float(xz[(size_t)gl * (2 * DI) + DI + d]);
        }
        float du = dtl * ul;
        float y = 0.f;
#pragma unroll
        for (int n = 0; n < NST; n++) {
            float a = __expf(dtl * Areg[n]);
            h[n] = a * h[n] + du * sBC[l * 32 + n];
            y += h[n] * sBC[l * 32 + NST + n];
        }
        float sz = zv / (1.f + __expf(-zv));
        yy[(size_t)(l0 + l) * DI + d] = __float2bfloat16((y + ul * Dd) * sz);
        dtl = dtn; ul = un; zv = zn;
    }
}

// ---------------------------------------------------------------------------
extern "C" void kernel_launch(void* const* d_in, const int* in_sizes, int n_in,
                              void* d_out, int out_size, void* d_ws, size_t ws_size,
                              hipStream_t stream) {
    const float* vst        = (const float*)d_in[0];
    const float* ln_w       = (const float*)d_in[1];
    const float* ln_b       = (const float*)d_in[2];
    const float* in_proj_w  = (const float*)d_in[3];
    const float* conv_w     = (const float*)d_in[4];
    const float* conv_b     = (const float*)d_in[5];
    const float* x_proj_w   = (const float*)d_in[6];
    const float* dt_proj_w  = (const float*)d_in[7];
    const float* dt_proj_b  = (const float*)d_in[8];
    const float* A_log      = (const float*)d_in[9];
    const float* D_param    = (const float*)d_in[10];
    const float* out_proj_w = (const float*)d_in[11];
    const float* fln_w      = (const float*)d_in[12];
    const float* fln_b      = (const float*)d_in[13];
    const float* mlp_w1     = (const float*)d_in[14];
    const float* mlp_b1     = (const float*)d_in[15];
    const float* mlp_w2     = (const float*)d_in[16];
    const float* mlp_b2     = (const float*)d_in[17];
    float* out = (float*)d_out;

    // ---------------- workspace layout ----------------
    char* wsb = (char*)d_ws;
    size_t off = 0;
    auto alloc_bf = [&](size_t n) { bf16_t* p = (bf16_t*)(wsb + off); off += n * 2; return p; };
    auto alloc_f  = [&](size_t n) { float*  p = (float*)(wsb + off); off += n * 4; return p; };

    // bf16 transposed weights
    bf16_t* w1t  = alloc_bf((size_t)(2 * DI) * DMODEL);   // [4096,1024]
    bf16_t* xpt  = alloc_bf((size_t)128 * DI);            // [128,2048] (96 padded)
    bf16_t* dtpt = alloc_bf((size_t)DI * DTRANK);         // [2048,64]
    bf16_t* opt  = alloc_bf((size_t)DMODEL * DI);         // [1024,2048]
    bf16_t* m1t  = alloc_bf((size_t)HID * DMODEL);        // [4096,1024]
    bf16_t* m2t  = alloc_bf((size_t)HID * HID);           // [4096,4096]
    // activations
    bf16_t* xz_bf   = alloc_bf((size_t)L_SEQ * 2 * DI);   // 33.5 MB
    bf16_t* u_bf    = alloc_bf((size_t)L_SEQ * DI);       // 16.8 MB
    bf16_t* dt_bf   = alloc_bf((size_t)L_SEQ * DI);       // 16.8 MB
    bf16_t* xdbl_bf = alloc_bf((size_t)L_SEQ * XDBL_N);
    bf16_t* yy_bf   = alloc_bf((size_t)L_SEQ * DI);       // 16.8 MB
    float*  xdbl_f  = alloc_f((size_t)L_SEQ * XDBL_N);
    float*  Pw      = alloc_f((size_t)NCHUNK * DI * NST); // 16.8 MB
    float*  Sw      = alloc_f((size_t)NCHUNK * DI * NST); // 16.8 MB (also init, in-place)
    // aliases over dead regions
    bf16_t* xn_bf   = yy_bf;           // LN1 out; dead before pass3 writes yy
    float*  g2part  = Pw;              // [8][4096][128] fp32 = 16.8 MB, dead before pass1
    float*  x2_f    = Pw;              // [4096][1024] fp32, live after pass2
    bf16_t* pooled  = dt_bf;           // dt dead after pass3
    bf16_t* h1_bf   = dt_bf + (size_t)POOLED_ROWS * DMODEL;
    float*  g5part  = (float*)yy_bf;   // [4][256][4096] fp32 = 16.8 MB, yy dead after G4
    float*  g6part  = (float*)xz_bf;   // [8][256][4096] fp32 = 33.5 MB, xz dead after pass3

    dim3 blk256(256);

    // 0) all weight transposes, one dispatch (job table matches kernel)
    transpose_all_kernel<<<27008, blk256, 0, stream>>>(
        in_proj_w, w1t, x_proj_w, xpt, dt_proj_w, dtpt,
        out_proj_w, opt, mlp_w1, m1t, mlp_w2, m2t);

    // 1) LN1: vst -> xn_bf
    ln_kernel<<<L_SEQ, blk256, 0, stream>>>(vst, ln_w, ln_b, xn_bf);

    // 2) G1: xz = xn @ in_proj  -> bf16 [L,4096]
    mfma_gemm<0><<<dim3((2 * DI) / 128, L_SEQ / 128), blk256, 0, stream>>>(
        xn_bf, DMODEL, w1t, DMODEL, DMODEL, nullptr, xz_bf, 2 * DI, nullptr, nullptr);

    // 3) conv+silu: xz[:,:DI] -> u_bf
    conv_silu_kernel<<<(L_SEQ * DI) / 256, blk256, 0, stream>>>(xz_bf, conv_w, conv_b, u_bf);

    // 4) G2 split-K(8): x_dbl = u @ x_proj  [4096,2048]x[2048,96->128]
    mfma_gemm_splitk<<<dim3(1, L_SEQ / 128, 8), blk256, 0, stream>>>(
        u_bf, DI, xpt, DI, DI / 8, g2part, 128, (size_t)L_SEQ * 128);
    reduce_splitk<8, 0><<<(L_SEQ * XDBL_N) / 256, blk256, 0, stream>>>(
        g2part, (size_t)L_SEQ * 128, 128, L_SEQ, XDBL_N, xdbl_f, xdbl_bf, XDBL_N, nullptr);

    // 5) G3: dt = softplus(x_dbl[:,:64] @ dt_proj + b) -> bf16 [L,2048]
    mfma_gemm<1><<<dim3(DI / 128, L_SEQ / 128), blk256, 0, stream>>>(
        xdbl_bf, XDBL_N, dtpt, DTRANK, DTRANK, nullptr, dt_bf, DI, dt_proj_b, nullptr);

    // 6-8) chunked selective scan (CHUNK=32, NCHUNK=128)
    scan_pass1<<<dim3(NCHUNK, DI / 64), dim3(64), 0, stream>>>(
        dt_bf, u_bf, xdbl_f, A_log, Pw, Sw);
    scan_pass2<<<(DI * NST) / 256, blk256, 0, stream>>>(Pw, Sw);
    scan_pass3<<<dim3(NCHUNK, DI / 64), dim3(64), 0, stream>>>(
        dt_bf, u_bf, xdbl_f, A_log, D_param, Sw, xz_bf, yy_bf);

    // 9) G4: x2 = vst + yy @ out_proj -> fp32 [L,1024]; 64x128 tiles, 512 blocks
    mfma_gemm64_res<<<dim3(DMODEL / 128, L_SEQ / 64), blk256, 0, stream>>>(
        yy_bf, DI, opt, DI, DI, x2_f, DMODEL, vst);

    // 10+11) fused LN2 + avgpool: x2 -> pooled bf16 [256,1024]
    ln_pool_kernel<<<POOLED_ROWS, blk256, 0, stream>>>(x2_f, fln_w, fln_b, pooled);

    // 12) G5 split-K(4): h1 = gelu(pooled @ mlp_w1 + b1) -> bf16 [256,4096]
    mfma_gemm_splitk<<<dim3(HID / 128, POOLED_ROWS / 128, 4), blk256, 0, stream>>>(
        pooled, DMODEL, m1t, DMODEL, DMODEL / 4, g5part, HID, (size_t)POOLED_ROWS * HID);
    reduce_splitk<4, 1><<<(POOLED_ROWS * HID) / 256, blk256, 0, stream>>>(
        g5part, (size_t)POOLED_ROWS * HID, HID, POOLED_ROWS, HID, nullptr, h1_bf, HID, mlp_b1);

    // 13) G6 split-K(8): out = h1 @ mlp_w2 + b2 -> fp32 [256,4096]
    mfma_gemm_splitk<<<dim3(HID / 128, POOLED_ROWS / 128, 8), blk256, 0, stream>>>(
        h1_bf, HID, m2t, HID, HID / 8, g6part, HID, (size_t)POOLED_ROWS * HID);
    reduce_splitk<8, 2><<<(POOLED_ROWS * HID) / 256, blk256, 0, stream>>>(
        g6part, (size_t)POOLED_ROWS * HID, HID, POOLED_ROWS, HID, out, nullptr, HID, mlp_b2);
}

// Round 6
// 493.125 us; speedup vs baseline: 5.8428x; 1.0075x over previous
//
#include <hip/hip_runtime.h>
#include <hip/hip_bf16.h>
#include <math.h>

typedef __hip_bfloat16 bf16_t;
typedef __attribute__((ext_vector_type(8))) short short8;
typedef __attribute__((ext_vector_type(4))) float f32x4;

// Problem constants
#define L_SEQ   4096      // F*P = 16*256
#define DMODEL  1024
#define DI      2048
#define NST     16
#define DTRANK  64
#define XDBL_N  96        // DTRANK + 2*NST
#define HID     4096
#define CHUNK   32
#define NCHUNK  128       // L_SEQ / CHUNK
#define POOLED_ROWS 256   // 16 frames * 4 * 4

// ---------------------------------------------------------------------------
// async global->LDS 16B copy (global_load_lds_dwordx4)
// ---------------------------------------------------------------------------
__device__ __forceinline__ void async_load16(const bf16_t* g, bf16_t* l) {
    __builtin_amdgcn_global_load_lds(
        (const __attribute__((address_space(1))) void*)g,
        (__attribute__((address_space(3))) void*)l,
        16, 0, 0);
}

__device__ __forceinline__ float bfbits2f(unsigned short b) {
    bf16_t h; *(unsigned short*)&h = b; return __bfloat162float(h);
}

// ---------------------------------------------------------------------------
// Fused transpose+convert, vectorized. 64x64 tiles.
// fp32 [K,N] row-major -> bf16 [Npad,K] row-major (pad rows zero).
// Reads float4; LDS t[n][k] stride 65 (2-way conflicts only); writes bf16x8.
// ---------------------------------------------------------------------------
__global__ __launch_bounds__(256)
void transpose_all_kernel(const float* __restrict__ j0, bf16_t* __restrict__ o0,
                          const float* __restrict__ j1, bf16_t* __restrict__ o1,
                          const float* __restrict__ j2, bf16_t* __restrict__ o2,
                          const float* __restrict__ j3, bf16_t* __restrict__ o3,
                          const float* __restrict__ j4, bf16_t* __restrict__ o4,
                          const float* __restrict__ j5, bf16_t* __restrict__ o5) {
    int b = blockIdx.x;
    const float* in; bf16_t* out; int K, N, Npad, local;
    if (b < 1024)       { in = j0; out = o0; K = 1024; N = 4096; Npad = 4096; local = b; }
    else if (b < 1088)  { in = j1; out = o1; K = 2048; N = 96;   Npad = 128;  local = b - 1024; }
    else if (b < 1120)  { in = j2; out = o2; K = 64;   N = 2048; Npad = 2048; local = b - 1088; }
    else if (b < 1632)  { in = j3; out = o3; K = 2048; N = 1024; Npad = 1024; local = b - 1120; }
    else if (b < 2656)  { in = j4; out = o4; K = 1024; N = 4096; Npad = 4096; local = b - 1632; }
    else                { in = j5; out = o5; K = 4096; N = 4096; Npad = 4096; local = b - 2656; }
    int nt = Npad >> 6;
    int k0 = (local / nt) << 6, n0 = (local % nt) << 6;

    __shared__ float t[64 * 65];     // t[n][k], stride 65
    int tid = threadIdx.x;
#pragma unroll
    for (int it = 0; it < 4; it++) {
        int slot = it * 256 + tid;
        int kk = slot >> 4, nq = (slot & 15) * 4;
        int gn = n0 + nq;
        const float* src = in + (size_t)(k0 + kk) * N + gn;
        float4 v;
        if (gn + 3 < N) v = *(const float4*)src;
        else {
            v.x = (gn + 0 < N) ? src[0] : 0.f;
            v.y = (gn + 1 < N) ? src[1] : 0.f;
            v.z = (gn + 2 < N) ? src[2] : 0.f;
            v.w = (gn + 3 < N) ? src[3] : 0.f;
        }
        t[(nq + 0) * 65 + kk] = v.x;
        t[(nq + 1) * 65 + kk] = v.y;
        t[(nq + 2) * 65 + kk] = v.z;
        t[(nq + 3) * 65 + kk] = v.w;
    }
    __syncthreads();
#pragma unroll
    for (int it = 0; it < 2; it++) {
        int slot = it * 256 + tid;
        int nn = slot >> 3, kc = (slot & 7) * 8;
        const float* r = &t[nn * 65 + kc];
        short8 o;
#pragma unroll
        for (int j = 0; j < 8; j++) {
            bf16_t h = __float2bfloat16(r[j]);
            o[j] = *(short*)&h;
        }
        *(short8*)(out + (size_t)(n0 + nn) * K + k0 + kc) = o;
    }
}

// ---------------------------------------------------------------------------
// LayerNorm: one block per row, 1024 cols -> bf16
// ---------------------------------------------------------------------------
__global__ __launch_bounds__(256)
void ln_kernel(const float* __restrict__ x, const float* __restrict__ w,
               const float* __restrict__ b, bf16_t* __restrict__ out) {
    int row = blockIdx.x;
    int tid = threadIdx.x;
    const float* xr = x + (size_t)row * DMODEL;
    float v[4];
    float s = 0.f, ss = 0.f;
#pragma unroll
    for (int e = 0; e < 4; e++) {
        v[e] = xr[tid + e * 256];
        s += v[e];
        ss += v[e] * v[e];
    }
#pragma unroll
    for (int off = 32; off > 0; off >>= 1) {
        s  += __shfl_down(s, off);
        ss += __shfl_down(ss, off);
    }
    __shared__ float rs[4], rss[4];
    int wid = tid >> 6;
    if ((tid & 63) == 0) { rs[wid] = s; rss[wid] = ss; }
    __syncthreads();
    s  = rs[0] + rs[1] + rs[2] + rs[3];
    ss = rss[0] + rss[1] + rss[2] + rss[3];
    float mu  = s * (1.f / DMODEL);
    float var = ss * (1.f / DMODEL) - mu * mu;
    float inv = rsqrtf(var + 1e-5f);
#pragma unroll
    for (int e = 0; e < 4; e++) {
        int col = tid + e * 256;
        out[(size_t)row * DMODEL + col] =
            __float2bfloat16((v[e] - mu) * inv * w[col] + b[col]);
    }
}

// ---------------------------------------------------------------------------
// Fused LN2 + AvgPool(1,4,4): block per pooled row; LN 16 source rows, avg.
// ---------------------------------------------------------------------------
__global__ __launch_bounds__(256)
void ln_pool_kernel(const float* __restrict__ x, const float* __restrict__ w,
                    const float* __restrict__ b, bf16_t* __restrict__ pooled) {
    int p = blockIdx.x;                  // 0..255
    int tid = threadIdx.x;
    int f = p >> 4, i4 = (p >> 2) & 3, j4 = p & 3;
    __shared__ float rs[4], rss[4];
    float acc[4] = {0.f, 0.f, 0.f, 0.f};
    float wv[4], bv[4];
#pragma unroll
    for (int e = 0; e < 4; e++) { wv[e] = w[tid + e * 256]; bv[e] = b[tid + e * 256]; }
    for (int r16 = 0; r16 < 16; r16++) {
        int ii = r16 >> 2, jj = r16 & 3;
        int row = f * 256 + (i4 * 4 + ii) * 16 + j4 * 4 + jj;
        const float* xr = x + (size_t)row * DMODEL;
        float v[4];
        float s = 0.f, ss = 0.f;
#pragma unroll
        for (int e = 0; e < 4; e++) {
            v[e] = xr[tid + e * 256];
            s += v[e];
            ss += v[e] * v[e];
        }
#pragma unroll
        for (int off = 32; off > 0; off >>= 1) {
            s  += __shfl_down(s, off);
            ss += __shfl_down(ss, off);
        }
        int wid = tid >> 6;
        if ((tid & 63) == 0) { rs[wid] = s; rss[wid] = ss; }
        __syncthreads();
        s  = rs[0] + rs[1] + rs[2] + rs[3];
        ss = rss[0] + rss[1] + rss[2] + rss[3];
        float mu  = s * (1.f / DMODEL);
        float var = ss * (1.f / DMODEL) - mu * mu;
        float inv = rsqrtf(var + 1e-5f);
#pragma unroll
        for (int e = 0; e < 4; e++)
            acc[e] += (v[e] - mu) * inv * wv[e] + bv[e];
        __syncthreads();
    }
#pragma unroll
    for (int e = 0; e < 4; e++)
        pooled[(size_t)p * DMODEL + tid + e * 256] = __float2bfloat16(acc[e] * (1.f / 16.f));
}

// ---------------------------------------------------------------------------
// bf16 MFMA GEMM: C[M,Nt] = epi(A[M,K] @ Bt[Nt,K]^T)
// 128x128 tile, BK=32, 256 threads (4 waves). EPI: 0 bf16; 1 bias+softplus bf16
// ---------------------------------------------------------------------------
template <int EPI>
__global__ __launch_bounds__(256, 2)
void mfma_gemm(const bf16_t* __restrict__ A, int lda,
               const bf16_t* __restrict__ Bt, int ldb,
               int K,
               float* __restrict__ Cf, bf16_t* __restrict__ Cb, int ldc,
               const float* __restrict__ bias, const float* __restrict__ res) {
    __shared__ bf16_t Asl[128 * 32];
    __shared__ bf16_t Bsl[128 * 32];
    const int tid = threadIdx.x;
    const int l = tid & 63, w = tid >> 6;
    const int m0 = blockIdx.y * 128, n0 = blockIdx.x * 128;
    const int wm = (w >> 1) * 64, wn = (w & 1) * 64;

    const int srow = tid >> 2;
    const int skc = (tid & 3) * 8;
    const bf16_t* Ag = A + (size_t)(m0 + srow) * lda + skc;
    const bf16_t* Bg = Bt + (size_t)(n0 + srow) * ldb + skc;
    bf16_t* As0 = Asl + (size_t)(w * 64) * 8;
    bf16_t* As1 = Asl + (size_t)(256 + w * 64) * 8;
    bf16_t* Bs0 = Bsl + (size_t)(w * 64) * 8;
    bf16_t* Bs1 = Bsl + (size_t)(256 + w * 64) * 8;

    f32x4 acc[4][4];
#pragma unroll
    for (int i = 0; i < 4; i++)
#pragma unroll
        for (int j = 0; j < 4; j++) acc[i][j] = (f32x4){0.f, 0.f, 0.f, 0.f};

    const short8* Asv = (const short8*)Asl;
    const short8* Bsv = (const short8*)Bsl;
    const int fr = l >> 4;
    const int fc = l & 15;

    for (int k0 = 0; k0 < K; k0 += 32) {
        __syncthreads();
        async_load16(Ag, As0);
        async_load16(Ag + (size_t)64 * lda, As1);
        async_load16(Bg, Bs0);
        async_load16(Bg + (size_t)64 * ldb, Bs1);
        Ag += 32; Bg += 32;
        __syncthreads();

        short8 a[4], b[4];
#pragma unroll
        for (int im = 0; im < 4; im++)
            a[im] = Asv[(wm + im * 16 + fc) * 4 + fr];
#pragma unroll
        for (int in = 0; in < 4; in++)
            b[in] = Bsv[(wn + in * 16 + fc) * 4 + fr];
#pragma unroll
        for (int im = 0; im < 4; im++)
#pragma unroll
            for (int in = 0; in < 4; in++)
                acc[im][in] = __builtin_amdgcn_mfma_f32_16x16x32_bf16(
                    a[im], b[in], acc[im][in], 0, 0, 0);
    }

#pragma unroll
    for (int im = 0; im < 4; im++) {
        int mbase = m0 + wm + im * 16 + fr * 4;
#pragma unroll
        for (int in = 0; in < 4; in++) {
            int n = n0 + wn + in * 16 + fc;
            float bv = (EPI == 1) ? bias[n] : 0.f;
#pragma unroll
            for (int v = 0; v < 4; v++) {
                float x = acc[im][in][v];
                size_t off = (size_t)(mbase + v) * ldc + n;
                if (EPI == 0) {
                    Cb[off] = __float2bfloat16(x);
                } else if (EPI == 1) {
                    x += bv;
                    x = (x > 20.f) ? x : log1pf(__expf(x));
                    Cb[off] = __float2bfloat16(x);
                }
            }
        }
    }
}

// ---------------------------------------------------------------------------
// Split-K variant: grid.z = K-split; partials fp32 (PBF16=0) or bf16 (PBF16=1)
// ---------------------------------------------------------------------------
template <bool PBF16>
__global__ __launch_bounds__(256, 2)
void mfma_gemm_splitk(const bf16_t* __restrict__ A, int lda,
                      const bf16_t* __restrict__ Bt, int ldb,
                      int Kper, void* __restrict__ Cpart, int ldc,
                      size_t pstride) {
    __shared__ bf16_t Asl[128 * 32];
    __shared__ bf16_t Bsl[128 * 32];
    const int tid = threadIdx.x;
    const int l = tid & 63, w = tid >> 6;
    const int m0 = blockIdx.y * 128, n0 = blockIdx.x * 128;
    const int wm = (w >> 1) * 64, wn = (w & 1) * 64;
    const int kbase = blockIdx.z * Kper;

    const int srow = tid >> 2;
    const int skc = (tid & 3) * 8;
    const bf16_t* Ag = A + (size_t)(m0 + srow) * lda + kbase + skc;
    const bf16_t* Bg = Bt + (size_t)(n0 + srow) * ldb + kbase + skc;
    bf16_t* As0 = Asl + (size_t)(w * 64) * 8;
    bf16_t* As1 = Asl + (size_t)(256 + w * 64) * 8;
    bf16_t* Bs0 = Bsl + (size_t)(w * 64) * 8;
    bf16_t* Bs1 = Bsl + (size_t)(256 + w * 64) * 8;

    f32x4 acc[4][4];
#pragma unroll
    for (int i = 0; i < 4; i++)
#pragma unroll
        for (int j = 0; j < 4; j++) acc[i][j] = (f32x4){0.f, 0.f, 0.f, 0.f};

    const short8* Asv = (const short8*)Asl;
    const short8* Bsv = (const short8*)Bsl;
    const int fr = l >> 4;
    const int fc = l & 15;

    for (int k0 = 0; k0 < Kper; k0 += 32) {
        __syncthreads();
        async_load16(Ag, As0);
        async_load16(Ag + (size_t)64 * lda, As1);
        async_load16(Bg, Bs0);
        async_load16(Bg + (size_t)64 * ldb, Bs1);
        Ag += 32; Bg += 32;
        __syncthreads();

        short8 a[4], b[4];
#pragma unroll
        for (int im = 0; im < 4; im++)
            a[im] = Asv[(wm + im * 16 + fc) * 4 + fr];
#pragma unroll
        for (int in = 0; in < 4; in++)
            b[in] = Bsv[(wn + in * 16 + fc) * 4 + fr];
#pragma unroll
        for (int im = 0; im < 4; im++)
#pragma unroll
            for (int in = 0; in < 4; in++)
                acc[im][in] = __builtin_amdgcn_mfma_f32_16x16x32_bf16(
                    a[im], b[in], acc[im][in], 0, 0, 0);
    }

#pragma unroll
    for (int im = 0; im < 4; im++) {
        int mbase = m0 + wm + im * 16 + fr * 4;
#pragma unroll
        for (int in = 0; in < 4; in++) {
            int n = n0 + wn + in * 16 + fc;
#pragma unroll
            for (int v = 0; v < 4; v++) {
                size_t o = (size_t)(mbase + v) * ldc + n;
                if (PBF16)
                    ((bf16_t*)Cpart)[(size_t)blockIdx.z * pstride + o] =
                        __float2bfloat16(acc[im][in][v]);
                else
                    ((float*)Cpart)[(size_t)blockIdx.z * pstride + o] = acc[im][in][v];
            }
        }
    }
}

// ---------------------------------------------------------------------------
// Split-K reduce (fp32 partials). EPI: 0 fp32+bf16; 1 bias+gelu bf16; 2 bias fp32
// ---------------------------------------------------------------------------
template <int S, int EPI>
__global__ __launch_bounds__(256)
void reduce_splitk(const float* __restrict__ part, size_t pstride, int ldp,
                   int M, int N, float* __restrict__ outf, bf16_t* __restrict__ outb,
                   int ldo, const float* __restrict__ bias) {
    int idx = blockIdx.x * 256 + threadIdx.x;
    if (idx >= M * N) return;
    int r = idx / N, c = idx - r * N;
    float s = 0.f;
#pragma unroll
    for (int z = 0; z < S; z++)
        s += part[(size_t)z * pstride + (size_t)r * ldp + c];
    size_t o = (size_t)r * ldo + c;
    if (EPI == 0) {
        outf[o] = s;
        outb[o] = __float2bfloat16(s);
    } else if (EPI == 1) {
        s += bias[c];
        s = 0.5f * s * (1.f + erff(s * 0.70710678118654752f));
        outb[o] = __float2bfloat16(s);
    } else {
        outf[o] = s + bias[c];
    }
}

// ---------------------------------------------------------------------------
// G4 reduce: 2 bf16 partial planes + fp32 residual -> fp32. Vectorized x4.
// ---------------------------------------------------------------------------
__global__ __launch_bounds__(256)
void reduce2_res_kernel(const bf16_t* __restrict__ part, size_t pstride,
                        const float* __restrict__ res, float* __restrict__ outf,
                        int total4) {
    int idx = blockIdx.x * 256 + threadIdx.x;
    if (idx >= total4) return;
    size_t o = (size_t)idx * 4;
    ushort4 p0 = *(const ushort4*)((const unsigned short*)part + o);
    ushort4 p1 = *(const ushort4*)((const unsigned short*)part + pstride + o);
    float4 r = *(const float4*)(res + o);
    float4 ov;
    ov.x = bfbits2f(p0.x) + bfbits2f(p1.x) + r.x;
    ov.y = bfbits2f(p0.y) + bfbits2f(p1.y) + r.y;
    ov.z = bfbits2f(p0.z) + bfbits2f(p1.z) + r.z;
    ov.w = bfbits2f(p0.w) + bfbits2f(p1.w) + r.w;
    *(float4*)(outf + o) = ov;
}

// ---------------------------------------------------------------------------
// Depthwise causal conv (k=4) + bias + silu. xin = xz[:, 0:DI] (bf16, ld 2*DI)
// ---------------------------------------------------------------------------
__global__ __launch_bounds__(256)
void conv_silu_kernel(const bf16_t* __restrict__ xz, const float* __restrict__ cw,
                      const float* __restrict__ cb, bf16_t* __restrict__ u) {
    int idx = blockIdx.x * 256 + threadIdx.x;      // over L_SEQ*DI
    if (idx >= L_SEQ * DI) return;
    int ch = idx & (DI - 1);
    int l  = idx >> 11;
    float acc = cb[ch];
#pragma unroll
    for (int k = 0; k < 4; k++) {
        int ls = l - 3 + k;
        if (ls >= 0)
            acc += cw[ch * 4 + k] * __bfloat162float(xz[(size_t)ls * (2 * DI) + ch]);
    }
    u[idx] = __float2bfloat16(acc / (1.f + __expf(-acc)));
}

// ---------------------------------------------------------------------------
// Selective scan pass 1 (lane-pair split): lanes l / l+32 share one channel d,
// each holds 8 of 16 states. 256 threads = 128 channels. Grid (NCHUNK, DI/128).
// P[n]=exp(A[n]*sum dt) once per chunk; S[n]=state from h=0.
// ---------------------------------------------------------------------------
__global__ __launch_bounds__(256)
void scan_pass1(const bf16_t* __restrict__ dt, const bf16_t* __restrict__ u,
                const float* __restrict__ x_dbl, const float* __restrict__ A_log,
                float* __restrict__ Pw, float* __restrict__ Sw) {
    int c = blockIdx.x;
    int tid = threadIdx.x;
    int lane = tid & 63, w = tid >> 6;
    int dloc = w * 32 + (lane & 31);
    int n0 = (lane >> 5) * 8;
    int d = blockIdx.y * 128 + dloc;
    int l0 = c * CHUNK;
    __shared__ float sB[CHUNK * NST];
    for (int i = tid; i < CHUNK * NST; i += 256)
        sB[i] = x_dbl[(size_t)(l0 + (i >> 4)) * XDBL_N + DTRANK + (i & 15)];
    __syncthreads();
    float Areg[8], h[8];
#pragma unroll
    for (int j = 0; j < 8; j++) {
        Areg[j] = -__expf(A_log[d * NST + n0 + j]);
        h[j] = 0.f;
    }
    float dts = 0.f;
    float dtl = __bfloat162float(dt[(size_t)l0 * DI + d]);
    float ul  = __bfloat162float(u[(size_t)l0 * DI + d]);
    for (int l = 0; l < CHUNK; l++) {
        float dtn = 0.f, un = 0.f;
        if (l + 1 < CHUNK) {
            int gl = l0 + l + 1;
            dtn = __bfloat162float(dt[(size_t)gl * DI + d]);
            un  = __bfloat162float(u[(size_t)gl * DI + d]);
        }
        float du = dtl * ul;
        dts += dtl;
#pragma unroll
        for (int j = 0; j < 8; j++) {
            float a = __expf(dtl * Areg[j]);
            h[j] = a * h[j] + du * sB[l * NST + n0 + j];
        }
        dtl = dtn; ul = un;
    }
    size_t base = ((size_t)c * DI + d) * NST + n0;
#pragma unroll
    for (int j = 0; j < 8; j++) {
        Pw[base + j] = __expf(dts * Areg[j]);
        Sw[base + j] = h[j];
    }
}

// ---------------------------------------------------------------------------
// Selective scan pass 2: sequential prefix over chunks; init in-place over Sw.
// ---------------------------------------------------------------------------
__global__ __launch_bounds__(256)
void scan_pass2(const float* __restrict__ Pw, float* __restrict__ SwInit) {
    int tid = blockIdx.x * 256 + threadIdx.x;   // 0 .. DI*NST-1
    if (tid >= DI * NST) return;
    float h = 0.f;
    for (int c = 0; c < NCHUNK; c++) {
        size_t idx = (size_t)c * (DI * NST) + tid;
        float s = SwInit[idx];
        SwInit[idx] = h;                 // becomes init state for chunk c
        h = Pw[idx] * h + s;
    }
}

// ---------------------------------------------------------------------------
// Selective scan pass 3 (lane-pair split): replay with init,
// yy = (h.C + u*D) * silu(z); y halves combined via shfl_xor(32).
// ---------------------------------------------------------------------------
__global__ __launch_bounds__(256)
void scan_pass3(const bf16_t* __restrict__ dt, const bf16_t* __restrict__ u,
                const float* __restrict__ x_dbl, const float* __restrict__ A_log,
                const float* __restrict__ Dp, const float* __restrict__ initw,
                const bf16_t* __restrict__ xz, bf16_t* __restrict__ yy) {
    int c = blockIdx.x;
    int tid = threadIdx.x;
    int lane = tid & 63, w = tid >> 6;
    int dloc = w * 32 + (lane & 31);
    int n0 = (lane >> 5) * 8;
    int d = blockIdx.y * 128 + dloc;
    int l0 = c * CHUNK;
    __shared__ float sBC[CHUNK * 2 * NST];
    for (int i = tid; i < CHUNK * 2 * NST; i += 256)
        sBC[i] = x_dbl[(size_t)(l0 + (i >> 5)) * XDBL_N + DTRANK + (i & 31)];
    __syncthreads();
    float Areg[8], h[8];
    size_t base = ((size_t)c * DI + d) * NST + n0;
#pragma unroll
    for (int j = 0; j < 8; j++) {
        Areg[j] = -__expf(A_log[d * NST + n0 + j]);
        h[j] = initw[base + j];
    }
    float Dd = Dp[d];
    float dtl = __bfloat162float(dt[(size_t)l0 * DI + d]);
    float ul  = __bfloat162float(u[(size_t)l0 * DI + d]);
    float zv  = __bfloat162float(xz[(size_t)l0 * (2 * DI) + DI + d]);
    for (int l = 0; l < CHUNK; l++) {
        float dtn = 0.f, un = 0.f, zn = 0.f;
        if (l + 1 < CHUNK) {
            int gl = l0 + l + 1;
            dtn = __bfloat162float(dt[(size_t)gl * DI + d]);
            un  = __bfloat162float(u[(size_t)gl * DI + d]);
            zn  = __bfloat162float(xz[(size_t)gl * (2 * DI) + DI + d]);
        }
        float du = dtl * ul;
        float y = 0.f;
#pragma unroll
        for (int j = 0; j < 8; j++) {
            float a = __expf(dtl * Areg[j]);
            h[j] = a * h[j] + du * sBC[l * 32 + n0 + j];
            y += h[j] * sBC[l * 32 + NST + n0 + j];
        }
        y += __shfl_xor(y, 32);
        float sz = zv / (1.f + __expf(-zv));
        if ((lane >> 5) == 0)
            yy[(size_t)(l0 + l) * DI + d] = __float2bfloat16((y + ul * Dd) * sz);
        dtl = dtn; ul = un; zv = zn;
    }
}

// ---------------------------------------------------------------------------
extern "C" void kernel_launch(void* const* d_in, const int* in_sizes, int n_in,
                              void* d_out, int out_size, void* d_ws, size_t ws_size,
                              hipStream_t stream) {
    const float* vst        = (const float*)d_in[0];
    const float* ln_w       = (const float*)d_in[1];
    const float* ln_b       = (const float*)d_in[2];
    const float* in_proj_w  = (const float*)d_in[3];
    const float* conv_w     = (const float*)d_in[4];
    const float* conv_b     = (const float*)d_in[5];
    const float* x_proj_w   = (const float*)d_in[6];
    const float* dt_proj_w  = (const float*)d_in[7];
    const float* dt_proj_b  = (const float*)d_in[8];
    const float* A_log      = (const float*)d_in[9];
    const float* D_param    = (const float*)d_in[10];
    const float* out_proj_w = (const float*)d_in[11];
    const float* fln_w      = (const float*)d_in[12];
    const float* fln_b      = (const float*)d_in[13];
    const float* mlp_w1     = (const float*)d_in[14];
    const float* mlp_b1     = (const float*)d_in[15];
    const float* mlp_w2     = (const float*)d_in[16];
    const float* mlp_b2     = (const float*)d_in[17];
    float* out = (float*)d_out;

    // ---------------- workspace layout ----------------
    char* wsb = (char*)d_ws;
    size_t off = 0;
    auto alloc_bf = [&](size_t n) { bf16_t* p = (bf16_t*)(wsb + off); off += n * 2; return p; };
    auto alloc_f  = [&](size_t n) { float*  p = (float*)(wsb + off); off += n * 4; return p; };

    // bf16 transposed weights
    bf16_t* w1t  = alloc_bf((size_t)(2 * DI) * DMODEL);   // [4096,1024]
    bf16_t* xpt  = alloc_bf((size_t)128 * DI);            // [128,2048] (96 padded)
    bf16_t* dtpt = alloc_bf((size_t)DI * DTRANK);         // [2048,64]
    bf16_t* opt  = alloc_bf((size_t)DMODEL * DI);         // [1024,2048]
    bf16_t* m1t  = alloc_bf((size_t)HID * DMODEL);        // [4096,1024]
    bf16_t* m2t  = alloc_bf((size_t)HID * HID);           // [4096,4096]
    // activations
    bf16_t* xz_bf   = alloc_bf((size_t)L_SEQ * 2 * DI);   // 33.5 MB
    bf16_t* u_bf    = alloc_bf((size_t)L_SEQ * DI);       // 16.8 MB
    bf16_t* dt_bf   = alloc_bf((size_t)L_SEQ * DI);       // 16.8 MB
    bf16_t* xdbl_bf = alloc_bf((size_t)L_SEQ * XDBL_N);
    bf16_t* yy_bf   = alloc_bf((size_t)L_SEQ * DI);       // 16.8 MB
    float*  xdbl_f  = alloc_f((size_t)L_SEQ * XDBL_N);
    float*  Pw      = alloc_f((size_t)NCHUNK * DI * NST); // 16.8 MB
    float*  Sw      = alloc_f((size_t)NCHUNK * DI * NST); // 16.8 MB (also init, in-place)
    // aliases over dead regions
    bf16_t* xn_bf   = yy_bf;           // LN1 out; dead before pass3 writes yy
    float*  g2part  = Pw;              // [8][4096][128] fp32 = 16.8 MB, dead before pass1
    float*  x2_f    = Pw;              // [4096][1024] fp32, live after pass2
    bf16_t* g4part  = xz_bf;           // [2][4096][1024] bf16 = 16.8 MB, xz dead after pass3
    bf16_t* pooled  = dt_bf;           // dt dead after pass3
    bf16_t* h1_bf   = dt_bf + (size_t)POOLED_ROWS * DMODEL;
    float*  g5part  = (float*)yy_bf;   // [4][256][4096] fp32 = 16.8 MB, yy dead after G4
    float*  g6part  = (float*)xz_bf;   // [8][256][4096] fp32 = 33.5 MB, g4part dead after reduce

    dim3 blk256(256);

    // 0) all weight transposes, one dispatch (6752 64x64 tiles)
    transpose_all_kernel<<<6752, blk256, 0, stream>>>(
        in_proj_w, w1t, x_proj_w, xpt, dt_proj_w, dtpt,
        out_proj_w, opt, mlp_w1, m1t, mlp_w2, m2t);

    // 1) LN1: vst -> xn_bf
    ln_kernel<<<L_SEQ, blk256, 0, stream>>>(vst, ln_w, ln_b, xn_bf);

    // 2) G1: xz = xn @ in_proj  -> bf16 [L,4096]
    mfma_gemm<0><<<dim3((2 * DI) / 128, L_SEQ / 128), blk256, 0, stream>>>(
        xn_bf, DMODEL, w1t, DMODEL, DMODEL, nullptr, xz_bf, 2 * DI, nullptr, nullptr);

    // 3) conv+silu: xz[:,:DI] -> u_bf
    conv_silu_kernel<<<(L_SEQ * DI) / 256, blk256, 0, stream>>>(xz_bf, conv_w, conv_b, u_bf);

    // 4) G2 split-K(8): x_dbl = u @ x_proj  [4096,2048]x[2048,96->128]
    mfma_gemm_splitk<false><<<dim3(1, L_SEQ / 128, 8), blk256, 0, stream>>>(
        u_bf, DI, xpt, DI, DI / 8, g2part, 128, (size_t)L_SEQ * 128);
    reduce_splitk<8, 0><<<(L_SEQ * XDBL_N) / 256, blk256, 0, stream>>>(
        g2part, (size_t)L_SEQ * 128, 128, L_SEQ, XDBL_N, xdbl_f, xdbl_bf, XDBL_N, nullptr);

    // 5) G3: dt = softplus(x_dbl[:,:64] @ dt_proj + b) -> bf16 [L,2048]
    mfma_gemm<1><<<dim3(DI / 128, L_SEQ / 128), blk256, 0, stream>>>(
        xdbl_bf, XDBL_N, dtpt, DTRANK, DTRANK, nullptr, dt_bf, DI, dt_proj_b, nullptr);

    // 6-8) chunked selective scan (CHUNK=32, lane-pair split: 32 waves/CU)
    scan_pass1<<<dim3(NCHUNK, DI / 128), blk256, 0, stream>>>(
        dt_bf, u_bf, xdbl_f, A_log, Pw, Sw);
    scan_pass2<<<(DI * NST) / 256, blk256, 0, stream>>>(Pw, Sw);
    scan_pass3<<<dim3(NCHUNK, DI / 128), blk256, 0, stream>>>(
        dt_bf, u_bf, xdbl_f, A_log, D_param, Sw, xz_bf, yy_bf);

    // 9) G4 split-K(2), bf16 partials: x2 = vst + yy @ out_proj -> fp32 [L,1024]
    mfma_gemm_splitk<true><<<dim3(DMODEL / 128, L_SEQ / 128, 2), blk256, 0, stream>>>(
        yy_bf, DI, opt, DI, DI / 2, g4part, DMODEL, (size_t)L_SEQ * DMODEL);
    reduce2_res_kernel<<<(L_SEQ * DMODEL / 4) / 256, blk256, 0, stream>>>(
        g4part, (size_t)L_SEQ * DMODEL, vst, x2_f, L_SEQ * DMODEL / 4);

    // 10+11) fused LN2 + avgpool: x2 -> pooled bf16 [256,1024]
    ln_pool_kernel<<<POOLED_ROWS, blk256, 0, stream>>>(x2_f, fln_w, fln_b, pooled);

    // 12) G5 split-K(4): h1 = gelu(pooled @ mlp_w1 + b1) -> bf16 [256,4096]
    mfma_gemm_splitk<false><<<dim3(HID / 128, POOLED_ROWS / 128, 4), blk256, 0, stream>>>(
        pooled, DMODEL, m1t, DMODEL, DMODEL / 4, g5part, HID, (size_t)POOLED_ROWS * HID);
    reduce_splitk<4, 1><<<(POOLED_ROWS * HID) / 256, blk256, 0, stream>>>(
        g5part, (size_t)POOLED_ROWS * HID, HID, POOLED_ROWS, HID, nullptr, h1_bf, HID, mlp_b1);

    // 13) G6 split-K(8): out = h1 @ mlp_w2 + b2 -> fp32 [256,4096]
    mfma_gemm_splitk<false><<<dim3(HID / 128, POOLED_ROWS / 128, 8), blk256, 0, stream>>>(
        h1_bf, HID, m2t, HID, HID / 8, g6part, HID, (size_t)POOLED_ROWS * HID);
    reduce_splitk<8, 2><<<(POOLED_ROWS * HID) / 256, blk256, 0, stream>>>(
        g6part, (size_t)POOLED_ROWS * HID, HID, POOLED_ROWS, HID, out, nullptr, HID, mlp_b2);
}

// Round 7
// 483.568 us; speedup vs baseline: 5.9583x; 1.0198x over previous
//
#include <hip/hip_runtime.h>
#include <hip/hip_bf16.h>
#include <math.h>

typedef __hip_bfloat16 bf16_t;
typedef __attribute__((ext_vector_type(8))) short short8;
typedef __attribute__((ext_vector_type(4))) float f32x4;

// Problem constants
#define L_SEQ   4096      // F*P = 16*256
#define DMODEL  1024
#define DI      2048
#define NST     16
#define DTRANK  64
#define XDBL_N  96        // DTRANK + 2*NST
#define HID     4096
#define CHUNK   32
#define NCHUNK  128       // L_SEQ / CHUNK
#define POOLED_ROWS 256   // 16 frames * 4 * 4

// ---------------------------------------------------------------------------
// async global->LDS 16B copy (global_load_lds_dwordx4)
// ---------------------------------------------------------------------------
__device__ __forceinline__ void async_load16(const bf16_t* g, bf16_t* l) {
    __builtin_amdgcn_global_load_lds(
        (const __attribute__((address_space(1))) void*)g,
        (__attribute__((address_space(3))) void*)l,
        16, 0, 0);
}

__device__ __forceinline__ float bfbits2f(unsigned short b) {
    bf16_t h; *(unsigned short*)&h = b; return __bfloat162float(h);
}

// ---------------------------------------------------------------------------
// Fused transpose+convert for all 6 weights. 128k x 64n tiles:
// 256 B read segments AND 256 B write segments. fp32 LDS [64][129] (2-way
// conflicts only, free). fp32 [K,N] -> bf16 [Npad,K], pad rows zero.
// tiles per job = ceil(K/128) * (Npad/64)
//   j0 in_proj  K=1024 N=4096 Npad=4096: 512   [0,512)
//   j1 x_proj   K=2048 N=96   Npad=128 :  32   [512,544)
//   j2 dt_proj  K=64   N=2048 Npad=2048:  32   [544,576)
//   j3 out_proj K=2048 N=1024 Npad=1024: 256   [576,832)
//   j4 mlp_w1   K=1024 N=4096 Npad=4096: 512   [832,1344)
//   j5 mlp_w2   K=4096 N=4096 Npad=4096: 2048  [1344,3392)
// ---------------------------------------------------------------------------
__global__ __launch_bounds__(256)
void transpose_all_kernel(const float* __restrict__ j0, bf16_t* __restrict__ o0,
                          const float* __restrict__ j1, bf16_t* __restrict__ o1,
                          const float* __restrict__ j2, bf16_t* __restrict__ o2,
                          const float* __restrict__ j3, bf16_t* __restrict__ o3,
                          const float* __restrict__ j4, bf16_t* __restrict__ o4,
                          const float* __restrict__ j5, bf16_t* __restrict__ o5) {
    int b = blockIdx.x;
    const float* in; bf16_t* out; int K, N, Npad, local;
    if (b < 512)        { in = j0; out = o0; K = 1024; N = 4096; Npad = 4096; local = b; }
    else if (b < 544)   { in = j1; out = o1; K = 2048; N = 96;   Npad = 128;  local = b - 512; }
    else if (b < 576)   { in = j2; out = o2; K = 64;   N = 2048; Npad = 2048; local = b - 544; }
    else if (b < 832)   { in = j3; out = o3; K = 2048; N = 1024; Npad = 1024; local = b - 576; }
    else if (b < 1344)  { in = j4; out = o4; K = 1024; N = 4096; Npad = 4096; local = b - 832; }
    else                { in = j5; out = o5; K = 4096; N = 4096; Npad = 4096; local = b - 1344; }
    int nt = Npad >> 6;
    int k0 = (local / nt) << 7, n0 = (local % nt) << 6;

    __shared__ float t[64 * 129];    // t[n][k], stride 129
    int tid = threadIdx.x;
    int kkb = tid >> 4;              // 0..15
    int nq  = (tid & 15) * 4;
#pragma unroll
    for (int it = 0; it < 8; it++) {
        int kl = it * 16 + kkb;      // 0..127
        int gk = k0 + kl, gn = n0 + nq;
        float4 v = {0.f, 0.f, 0.f, 0.f};
        if (gk < K) {
            const float* src = in + (size_t)gk * N + gn;
            if (gn + 3 < N) v = *(const float4*)src;
            else {
                if (gn + 0 < N) v.x = src[0];
                if (gn + 1 < N) v.y = src[1];
                if (gn + 2 < N) v.z = src[2];
                if (gn + 3 < N) v.w = src[3];
            }
        }
        t[(nq + 0) * 129 + kl] = v.x;
        t[(nq + 1) * 129 + kl] = v.y;
        t[(nq + 2) * 129 + kl] = v.z;
        t[(nq + 3) * 129 + kl] = v.w;
    }
    __syncthreads();
#pragma unroll
    for (int it = 0; it < 4; it++) {
        int slot = it * 256 + tid;
        int nn = slot >> 4, kc = (slot & 15) * 8;
        if (k0 + kc >= K) continue;
        const float* r = &t[nn * 129 + kc];
        short8 o;
#pragma unroll
        for (int j = 0; j < 8; j++) {
            bf16_t h = __float2bfloat16(r[j]);
            o[j] = *(short*)&h;
        }
        *(short8*)(out + (size_t)(n0 + nn) * K + k0 + kc) = o;
    }
}

// ---------------------------------------------------------------------------
// LayerNorm: one block per row, 1024 cols -> bf16
// ---------------------------------------------------------------------------
__global__ __launch_bounds__(256)
void ln_kernel(const float* __restrict__ x, const float* __restrict__ w,
               const float* __restrict__ b, bf16_t* __restrict__ out) {
    int row = blockIdx.x;
    int tid = threadIdx.x;
    const float* xr = x + (size_t)row * DMODEL;
    float v[4];
    float s = 0.f, ss = 0.f;
#pragma unroll
    for (int e = 0; e < 4; e++) {
        v[e] = xr[tid + e * 256];
        s += v[e];
        ss += v[e] * v[e];
    }
#pragma unroll
    for (int off = 32; off > 0; off >>= 1) {
        s  += __shfl_down(s, off);
        ss += __shfl_down(ss, off);
    }
    __shared__ float rs[4], rss[4];
    int wid = tid >> 6;
    if ((tid & 63) == 0) { rs[wid] = s; rss[wid] = ss; }
    __syncthreads();
    s  = rs[0] + rs[1] + rs[2] + rs[3];
    ss = rss[0] + rss[1] + rss[2] + rss[3];
    float mu  = s * (1.f / DMODEL);
    float var = ss * (1.f / DMODEL) - mu * mu;
    float inv = rsqrtf(var + 1e-5f);
#pragma unroll
    for (int e = 0; e < 4; e++) {
        int col = tid + e * 256;
        out[(size_t)row * DMODEL + col] =
            __float2bfloat16((v[e] - mu) * inv * w[col] + b[col]);
    }
}

// ---------------------------------------------------------------------------
// Fused G4-reduce(2 bf16 planes) + residual + LN2 + AvgPool(1,4,4).
// x2[row][col] = res + bf(p0) + bf(p1) computed on the fly; never materialized.
// ---------------------------------------------------------------------------
__global__ __launch_bounds__(256)
void ln_pool2_kernel(const bf16_t* __restrict__ part, size_t pstride,
                     const float* __restrict__ res, const float* __restrict__ w,
                     const float* __restrict__ b, bf16_t* __restrict__ pooled) {
    int p = blockIdx.x;                  // 0..255
    int tid = threadIdx.x;
    int f = p >> 4, i4 = (p >> 2) & 3, j4 = p & 3;
    __shared__ float rs[4], rss[4];
    float acc[4] = {0.f, 0.f, 0.f, 0.f};
    float wv[4], bv[4];
#pragma unroll
    for (int e = 0; e < 4; e++) { wv[e] = w[tid + e * 256]; bv[e] = b[tid + e * 256]; }
    for (int r16 = 0; r16 < 16; r16++) {
        int ii = r16 >> 2, jj = r16 & 3;
        int row = f * 256 + (i4 * 4 + ii) * 16 + j4 * 4 + jj;
        size_t ro = (size_t)row * DMODEL;
        float v[4];
        float s = 0.f, ss = 0.f;
#pragma unroll
        for (int e = 0; e < 4; e++) {
            int col = tid + e * 256;
            float x = res[ro + col]
                    + __bfloat162float(part[ro + col])
                    + __bfloat162float(part[pstride + ro + col]);
            v[e] = x;
            s += x;
            ss += x * x;
        }
#pragma unroll
        for (int off = 32; off > 0; off >>= 1) {
            s  += __shfl_down(s, off);
            ss += __shfl_down(ss, off);
        }
        int wid = tid >> 6;
        if ((tid & 63) == 0) { rs[wid] = s; rss[wid] = ss; }
        __syncthreads();
        s  = rs[0] + rs[1] + rs[2] + rs[3];
        ss = rss[0] + rss[1] + rss[2] + rss[3];
        float mu  = s * (1.f / DMODEL);
        float var = ss * (1.f / DMODEL) - mu * mu;
        float inv = rsqrtf(var + 1e-5f);
#pragma unroll
        for (int e = 0; e < 4; e++)
            acc[e] += (v[e] - mu) * inv * wv[e] + bv[e];
        __syncthreads();
    }
#pragma unroll
    for (int e = 0; e < 4; e++)
        pooled[(size_t)p * DMODEL + tid + e * 256] = __float2bfloat16(acc[e] * (1.f / 16.f));
}

// ---------------------------------------------------------------------------
// bf16 MFMA GEMM: C[M,Nt] = epi(A[M,K] @ Bt[Nt,K]^T)
// 128x128 tile, BK=32, 256 threads (4 waves). EPI: 0 bf16; 1 bias+softplus bf16
// ---------------------------------------------------------------------------
template <int EPI>
__global__ __launch_bounds__(256, 2)
void mfma_gemm(const bf16_t* __restrict__ A, int lda,
               const bf16_t* __restrict__ Bt, int ldb,
               int K,
               float* __restrict__ Cf, bf16_t* __restrict__ Cb, int ldc,
               const float* __restrict__ bias, const float* __restrict__ res) {
    __shared__ bf16_t Asl[128 * 32];
    __shared__ bf16_t Bsl[128 * 32];
    const int tid = threadIdx.x;
    const int l = tid & 63, w = tid >> 6;
    const int m0 = blockIdx.y * 128, n0 = blockIdx.x * 128;
    const int wm = (w >> 1) * 64, wn = (w & 1) * 64;

    const int srow = tid >> 2;
    const int skc = (tid & 3) * 8;
    const bf16_t* Ag = A + (size_t)(m0 + srow) * lda + skc;
    const bf16_t* Bg = Bt + (size_t)(n0 + srow) * ldb + skc;
    bf16_t* As0 = Asl + (size_t)(w * 64) * 8;
    bf16_t* As1 = Asl + (size_t)(256 + w * 64) * 8;
    bf16_t* Bs0 = Bsl + (size_t)(w * 64) * 8;
    bf16_t* Bs1 = Bsl + (size_t)(256 + w * 64) * 8;

    f32x4 acc[4][4];
#pragma unroll
    for (int i = 0; i < 4; i++)
#pragma unroll
        for (int j = 0; j < 4; j++) acc[i][j] = (f32x4){0.f, 0.f, 0.f, 0.f};

    const short8* Asv = (const short8*)Asl;
    const short8* Bsv = (const short8*)Bsl;
    const int fr = l >> 4;
    const int fc = l & 15;

    for (int k0 = 0; k0 < K; k0 += 32) {
        __syncthreads();
        async_load16(Ag, As0);
        async_load16(Ag + (size_t)64 * lda, As1);
        async_load16(Bg, Bs0);
        async_load16(Bg + (size_t)64 * ldb, Bs1);
        Ag += 32; Bg += 32;
        __syncthreads();

        short8 a[4], b[4];
#pragma unroll
        for (int im = 0; im < 4; im++)
            a[im] = Asv[(wm + im * 16 + fc) * 4 + fr];
#pragma unroll
        for (int in = 0; in < 4; in++)
            b[in] = Bsv[(wn + in * 16 + fc) * 4 + fr];
#pragma unroll
        for (int im = 0; im < 4; im++)
#pragma unroll
            for (int in = 0; in < 4; in++)
                acc[im][in] = __builtin_amdgcn_mfma_f32_16x16x32_bf16(
                    a[im], b[in], acc[im][in], 0, 0, 0);
    }

#pragma unroll
    for (int im = 0; im < 4; im++) {
        int mbase = m0 + wm + im * 16 + fr * 4;
#pragma unroll
        for (int in = 0; in < 4; in++) {
            int n = n0 + wn + in * 16 + fc;
            float bv = (EPI == 1) ? bias[n] : 0.f;
#pragma unroll
            for (int v = 0; v < 4; v++) {
                float x = acc[im][in][v];
                size_t off = (size_t)(mbase + v) * ldc + n;
                if (EPI == 0) {
                    Cb[off] = __float2bfloat16(x);
                } else if (EPI == 1) {
                    x += bv;
                    x = (x > 20.f) ? x : log1pf(__expf(x));
                    Cb[off] = __float2bfloat16(x);
                }
            }
        }
    }
}

// ---------------------------------------------------------------------------
// Split-K variant: grid.z = K-split; partials fp32 (PBF16=0) or bf16 (PBF16=1)
// ---------------------------------------------------------------------------
template <bool PBF16>
__global__ __launch_bounds__(256, 2)
void mfma_gemm_splitk(const bf16_t* __restrict__ A, int lda,
                      const bf16_t* __restrict__ Bt, int ldb,
                      int Kper, void* __restrict__ Cpart, int ldc,
                      size_t pstride) {
    __shared__ bf16_t Asl[128 * 32];
    __shared__ bf16_t Bsl[128 * 32];
    const int tid = threadIdx.x;
    const int l = tid & 63, w = tid >> 6;
    const int m0 = blockIdx.y * 128, n0 = blockIdx.x * 128;
    const int wm = (w >> 1) * 64, wn = (w & 1) * 64;
    const int kbase = blockIdx.z * Kper;

    const int srow = tid >> 2;
    const int skc = (tid & 3) * 8;
    const bf16_t* Ag = A + (size_t)(m0 + srow) * lda + kbase + skc;
    const bf16_t* Bg = Bt + (size_t)(n0 + srow) * ldb + kbase + skc;
    bf16_t* As0 = Asl + (size_t)(w * 64) * 8;
    bf16_t* As1 = Asl + (size_t)(256 + w * 64) * 8;
    bf16_t* Bs0 = Bsl + (size_t)(w * 64) * 8;
    bf16_t* Bs1 = Bsl + (size_t)(256 + w * 64) * 8;

    f32x4 acc[4][4];
#pragma unroll
    for (int i = 0; i < 4; i++)
#pragma unroll
        for (int j = 0; j < 4; j++) acc[i][j] = (f32x4){0.f, 0.f, 0.f, 0.f};

    const short8* Asv = (const short8*)Asl;
    const short8* Bsv = (const short8*)Bsl;
    const int fr = l >> 4;
    const int fc = l & 15;

    for (int k0 = 0; k0 < Kper; k0 += 32) {
        __syncthreads();
        async_load16(Ag, As0);
        async_load16(Ag + (size_t)64 * lda, As1);
        async_load16(Bg, Bs0);
        async_load16(Bg + (size_t)64 * ldb, Bs1);
        Ag += 32; Bg += 32;
        __syncthreads();

        short8 a[4], b[4];
#pragma unroll
        for (int im = 0; im < 4; im++)
            a[im] = Asv[(wm + im * 16 + fc) * 4 + fr];
#pragma unroll
        for (int in = 0; in < 4; in++)
            b[in] = Bsv[(wn + in * 16 + fc) * 4 + fr];
#pragma unroll
        for (int im = 0; im < 4; im++)
#pragma unroll
            for (int in = 0; in < 4; in++)
                acc[im][in] = __builtin_amdgcn_mfma_f32_16x16x32_bf16(
                    a[im], b[in], acc[im][in], 0, 0, 0);
    }

#pragma unroll
    for (int im = 0; im < 4; im++) {
        int mbase = m0 + wm + im * 16 + fr * 4;
#pragma unroll
        for (int in = 0; in < 4; in++) {
            int n = n0 + wn + in * 16 + fc;
#pragma unroll
            for (int v = 0; v < 4; v++) {
                size_t o = (size_t)(mbase + v) * ldc + n;
                if (PBF16)
                    ((bf16_t*)Cpart)[(size_t)blockIdx.z * pstride + o] =
                        __float2bfloat16(acc[im][in][v]);
                else
                    ((float*)Cpart)[(size_t)blockIdx.z * pstride + o] = acc[im][in][v];
            }
        }
    }
}

// ---------------------------------------------------------------------------
// Split-K reduce (fp32 partials). EPI: 0 fp32+bf16; 1 bias+gelu bf16; 2 bias fp32
// ---------------------------------------------------------------------------
template <int S, int EPI>
__global__ __launch_bounds__(256)
void reduce_splitk(const float* __restrict__ part, size_t pstride, int ldp,
                   int M, int N, float* __restrict__ outf, bf16_t* __restrict__ outb,
                   int ldo, const float* __restrict__ bias) {
    int idx = blockIdx.x * 256 + threadIdx.x;
    if (idx >= M * N) return;
    int r = idx / N, c = idx - r * N;
    float s = 0.f;
#pragma unroll
    for (int z = 0; z < S; z++)
        s += part[(size_t)z * pstride + (size_t)r * ldp + c];
    size_t o = (size_t)r * ldo + c;
    if (EPI == 0) {
        outf[o] = s;
        outb[o] = __float2bfloat16(s);
    } else if (EPI == 1) {
        s += bias[c];
        s = 0.5f * s * (1.f + erff(s * 0.70710678118654752f));
        outb[o] = __float2bfloat16(s);
    } else {
        outf[o] = s + bias[c];
    }
}

// ---------------------------------------------------------------------------
// Depthwise causal conv (k=4) + bias + silu. xin = xz[:, 0:DI] (bf16, ld 2*DI)
// ---------------------------------------------------------------------------
__global__ __launch_bounds__(256)
void conv_silu_kernel(const bf16_t* __restrict__ xz, const float* __restrict__ cw,
                      const float* __restrict__ cb, bf16_t* __restrict__ u) {
    int idx = blockIdx.x * 256 + threadIdx.x;      // over L_SEQ*DI
    if (idx >= L_SEQ * DI) return;
    int ch = idx & (DI - 1);
    int l  = idx >> 11;
    float acc = cb[ch];
#pragma unroll
    for (int k = 0; k < 4; k++) {
        int ls = l - 3 + k;
        if (ls >= 0)
            acc += cw[ch * 4 + k] * __bfloat162float(xz[(size_t)ls * (2 * DI) + ch]);
    }
    u[idx] = __float2bfloat16(acc / (1.f + __expf(-acc)));
}

// ---------------------------------------------------------------------------
// Selective scan pass 1 (lane-pair split): lanes l / l+32 share one channel d,
// each holds 8 of 16 states. 256 threads = 128 channels. Grid (NCHUNK, DI/128).
// ---------------------------------------------------------------------------
__global__ __launch_bounds__(256)
void scan_pass1(const bf16_t* __restrict__ dt, const bf16_t* __restrict__ u,
                const float* __restrict__ x_dbl, const float* __restrict__ A_log,
                float* __restrict__ Pw, float* __restrict__ Sw) {
    int c = blockIdx.x;
    int tid = threadIdx.x;
    int lane = tid & 63, w = tid >> 6;
    int dloc = w * 32 + (lane & 31);
    int n0 = (lane >> 5) * 8;
    int d = blockIdx.y * 128 + dloc;
    int l0 = c * CHUNK;
    __shared__ float sB[CHUNK * NST];
    for (int i = tid; i < CHUNK * NST; i += 256)
        sB[i] = x_dbl[(size_t)(l0 + (i >> 4)) * XDBL_N + DTRANK + (i & 15)];
    __syncthreads();
    float Areg[8], h[8];
#pragma unroll
    for (int j = 0; j < 8; j++) {
        Areg[j] = -__expf(A_log[d * NST + n0 + j]);
        h[j] = 0.f;
    }
    float dts = 0.f;
    float dtl = __bfloat162float(dt[(size_t)l0 * DI + d]);
    float ul  = __bfloat162float(u[(size_t)l0 * DI + d]);
    for (int l = 0; l < CHUNK; l++) {
        float dtn = 0.f, un = 0.f;
        if (l + 1 < CHUNK) {
            int gl = l0 + l + 1;
            dtn = __bfloat162float(dt[(size_t)gl * DI + d]);
            un  = __bfloat162float(u[(size_t)gl * DI + d]);
        }
        float du = dtl * ul;
        dts += dtl;
#pragma unroll
        for (int j = 0; j < 8; j++) {
            float a = __expf(dtl * Areg[j]);
            h[j] = a * h[j] + du * sB[l * NST + n0 + j];
        }
        dtl = dtn; ul = un;
    }
    size_t base = ((size_t)c * DI + d) * NST + n0;
#pragma unroll
    for (int j = 0; j < 8; j++) {
        Pw[base + j] = __expf(dts * Areg[j]);
        Sw[base + j] = h[j];
    }
}

// ---------------------------------------------------------------------------
// Selective scan pass 2: sequential prefix over chunks; init in-place over Sw.
// One-chunk-ahead register prefetch of P/S.
// ---------------------------------------------------------------------------
__global__ __launch_bounds__(256)
void scan_pass2(const float* __restrict__ Pw, float* __restrict__ SwInit) {
    int tid = blockIdx.x * 256 + threadIdx.x;   // 0 .. DI*NST-1
    if (tid >= DI * NST) return;
    const int DN = DI * NST;
    size_t idx = tid;
    float h = 0.f;
    float p = Pw[idx], s = SwInit[idx];
    for (int c = 0; c < NCHUNK; c++) {
        size_t nidx = idx + DN;
        float pn = 0.f, sn = 0.f;
        if (c + 1 < NCHUNK) { pn = Pw[nidx]; sn = SwInit[nidx]; }
        SwInit[idx] = h;                 // becomes init state for chunk c
        h = p * h + s;
        p = pn; s = sn; idx = nidx;
    }
}

// ---------------------------------------------------------------------------
// Selective scan pass 3 (lane-pair split): replay with init,
// yy = (h.C + u*D) * silu(z); y halves combined via shfl_xor(32).
// ---------------------------------------------------------------------------
__global__ __launch_bounds__(256)
void scan_pass3(const bf16_t* __restrict__ dt, const bf16_t* __restrict__ u,
                const float* __restrict__ x_dbl, const float* __restrict__ A_log,
                const float* __restrict__ Dp, const float* __restrict__ initw,
                const bf16_t* __restrict__ xz, bf16_t* __restrict__ yy) {
    int c = blockIdx.x;
    int tid = threadIdx.x;
    int lane = tid & 63, w = tid >> 6;
    int dloc = w * 32 + (lane & 31);
    int n0 = (lane >> 5) * 8;
    int d = blockIdx.y * 128 + dloc;
    int l0 = c * CHUNK;
    __shared__ float sBC[CHUNK * 2 * NST];
    for (int i = tid; i < CHUNK * 2 * NST; i += 256)
        sBC[i] = x_dbl[(size_t)(l0 + (i >> 5)) * XDBL_N + DTRANK + (i & 31)];
    __syncthreads();
    float Areg[8], h[8];
    size_t base = ((size_t)c * DI + d) * NST + n0;
#pragma unroll
    for (int j = 0; j < 8; j++) {
        Areg[j] = -__expf(A_log[d * NST + n0 + j]);
        h[j] = initw[base + j];
    }
    float Dd = Dp[d];
    float dtl = __bfloat162float(dt[(size_t)l0 * DI + d]);
    float ul  = __bfloat162float(u[(size_t)l0 * DI + d]);
    float zv  = __bfloat162float(xz[(size_t)l0 * (2 * DI) + DI + d]);
    for (int l = 0; l < CHUNK; l++) {
        float dtn = 0.f, un = 0.f, zn = 0.f;
        if (l + 1 < CHUNK) {
            int gl = l0 + l + 1;
            dtn = __bfloat162float(dt[(size_t)gl * DI + d]);
            un  = __bfloat162float(u[(size_t)gl * DI + d]);
            zn  = __bfloat162float(xz[(size_t)gl * (2 * DI) + DI + d]);
        }
        float du = dtl * ul;
        float y = 0.f;
#pragma unroll
        for (int j = 0; j < 8; j++) {
            float a = __expf(dtl * Areg[j]);
            h[j] = a * h[j] + du * sBC[l * 32 + n0 + j];
            y += h[j] * sBC[l * 32 + NST + n0 + j];
        }
        y += __shfl_xor(y, 32);
        float sz = zv / (1.f + __expf(-zv));
        if ((lane >> 5) == 0)
            yy[(size_t)(l0 + l) * DI + d] = __float2bfloat16((y + ul * Dd) * sz);
        dtl = dtn; ul = un; zv = zn;
    }
}

// ---------------------------------------------------------------------------
extern "C" void kernel_launch(void* const* d_in, const int* in_sizes, int n_in,
                              void* d_out, int out_size, void* d_ws, size_t ws_size,
                              hipStream_t stream) {
    const float* vst        = (const float*)d_in[0];
    const float* ln_w       = (const float*)d_in[1];
    const float* ln_b       = (const float*)d_in[2];
    const float* in_proj_w  = (const float*)d_in[3];
    const float* conv_w     = (const float*)d_in[4];
    const float* conv_b     = (const float*)d_in[5];
    const float* x_proj_w   = (const float*)d_in[6];
    const float* dt_proj_w  = (const float*)d_in[7];
    const float* dt_proj_b  = (const float*)d_in[8];
    const float* A_log      = (const float*)d_in[9];
    const float* D_param    = (const float*)d_in[10];
    const float* out_proj_w = (const float*)d_in[11];
    const float* fln_w      = (const float*)d_in[12];
    const float* fln_b      = (const float*)d_in[13];
    const float* mlp_w1     = (const float*)d_in[14];
    const float* mlp_b1     = (const float*)d_in[15];
    const float* mlp_w2     = (const float*)d_in[16];
    const float* mlp_b2     = (const float*)d_in[17];
    float* out = (float*)d_out;

    // ---------------- workspace layout ----------------
    char* wsb = (char*)d_ws;
    size_t off = 0;
    auto alloc_bf = [&](size_t n) { bf16_t* p = (bf16_t*)(wsb + off); off += n * 2; return p; };
    auto alloc_f  = [&](size_t n) { float*  p = (float*)(wsb + off); off += n * 4; return p; };

    // bf16 transposed weights
    bf16_t* w1t  = alloc_bf((size_t)(2 * DI) * DMODEL);   // [4096,1024]
    bf16_t* xpt  = alloc_bf((size_t)128 * DI);            // [128,2048] (96 padded)
    bf16_t* dtpt = alloc_bf((size_t)DI * DTRANK);         // [2048,64]
    bf16_t* opt  = alloc_bf((size_t)DMODEL * DI);         // [1024,2048]
    bf16_t* m1t  = alloc_bf((size_t)HID * DMODEL);        // [4096,1024]
    bf16_t* m2t  = alloc_bf((size_t)HID * HID);           // [4096,4096]
    // activations
    bf16_t* xz_bf   = alloc_bf((size_t)L_SEQ * 2 * DI);   // 33.5 MB
    bf16_t* u_bf    = alloc_bf((size_t)L_SEQ * DI);       // 16.8 MB
    bf16_t* dt_bf   = alloc_bf((size_t)L_SEQ * DI);       // 16.8 MB
    bf16_t* xdbl_bf = alloc_bf((size_t)L_SEQ * XDBL_N);
    bf16_t* yy_bf   = alloc_bf((size_t)L_SEQ * DI);       // 16.8 MB
    float*  xdbl_f  = alloc_f((size_t)L_SEQ * XDBL_N);
    float*  Pw      = alloc_f((size_t)NCHUNK * DI * NST); // 16.8 MB
    float*  Sw      = alloc_f((size_t)NCHUNK * DI * NST); // 16.8 MB (also init, in-place)
    // aliases over dead regions
    bf16_t* xn_bf   = yy_bf;           // LN1 out; dead before pass3 writes yy
    float*  g2part  = Pw;              // [8][4096][128] fp32 = 16.8 MB, dead before pass1
    bf16_t* g4part  = xz_bf;           // [2][4096][1024] bf16 = 16.8 MB, xz dead after pass3
    bf16_t* pooled  = dt_bf;           // dt dead after pass3
    bf16_t* h1_bf   = dt_bf + (size_t)POOLED_ROWS * DMODEL;
    float*  g5part  = (float*)yy_bf;   // [4][256][4096] fp32 = 16.8 MB, yy dead after G4
    float*  g6part  = (float*)xz_bf;   // [8][256][4096] fp32 = 33.5 MB, g4part dead after pool

    dim3 blk256(256);

    // 0) all weight transposes, one dispatch (3392 128x64 tiles)
    transpose_all_kernel<<<3392, blk256, 0, stream>>>(
        in_proj_w, w1t, x_proj_w, xpt, dt_proj_w, dtpt,
        out_proj_w, opt, mlp_w1, m1t, mlp_w2, m2t);

    // 1) LN1: vst -> xn_bf
    ln_kernel<<<L_SEQ, blk256, 0, stream>>>(vst, ln_w, ln_b, xn_bf);

    // 2) G1: xz = xn @ in_proj  -> bf16 [L,4096]
    mfma_gemm<0><<<dim3((2 * DI) / 128, L_SEQ / 128), blk256, 0, stream>>>(
        xn_bf, DMODEL, w1t, DMODEL, DMODEL, nullptr, xz_bf, 2 * DI, nullptr, nullptr);

    // 3) conv+silu: xz[:,:DI] -> u_bf
    conv_silu_kernel<<<(L_SEQ * DI) / 256, blk256, 0, stream>>>(xz_bf, conv_w, conv_b, u_bf);

    // 4) G2 split-K(8): x_dbl = u @ x_proj  [4096,2048]x[2048,96->128]
    mfma_gemm_splitk<false><<<dim3(1, L_SEQ / 128, 8), blk256, 0, stream>>>(
        u_bf, DI, xpt, DI, DI / 8, g2part, 128, (size_t)L_SEQ * 128);
    reduce_splitk<8, 0><<<(L_SEQ * XDBL_N) / 256, blk256, 0, stream>>>(
        g2part, (size_t)L_SEQ * 128, 128, L_SEQ, XDBL_N, xdbl_f, xdbl_bf, XDBL_N, nullptr);

    // 5) G3: dt = softplus(x_dbl[:,:64] @ dt_proj + b) -> bf16 [L,2048]
    mfma_gemm<1><<<dim3(DI / 128, L_SEQ / 128), blk256, 0, stream>>>(
        xdbl_bf, XDBL_N, dtpt, DTRANK, DTRANK, nullptr, dt_bf, DI, dt_proj_b, nullptr);

    // 6-8) chunked selective scan (CHUNK=32, lane-pair split: 32 waves/CU)
    scan_pass1<<<dim3(NCHUNK, DI / 128), blk256, 0, stream>>>(
        dt_bf, u_bf, xdbl_f, A_log, Pw, Sw);
    scan_pass2<<<(DI * NST) / 256, blk256, 0, stream>>>(Pw, Sw);
    scan_pass3<<<dim3(NCHUNK, DI / 128), blk256, 0, stream>>>(
        dt_bf, u_bf, xdbl_f, A_log, D_param, Sw, xz_bf, yy_bf);

    // 9) G4 split-K(2), bf16 partials: yy @ out_proj (residual folded into pool)
    mfma_gemm_splitk<true><<<dim3(DMODEL / 128, L_SEQ / 128, 2), blk256, 0, stream>>>(
        yy_bf, DI, opt, DI, DI / 2, g4part, DMODEL, (size_t)L_SEQ * DMODEL);

    // 10) fused G4-reduce + residual + LN2 + avgpool -> pooled bf16 [256,1024]
    ln_pool2_kernel<<<POOLED_ROWS, blk256, 0, stream>>>(
        g4part, (size_t)L_SEQ * DMODEL, vst, fln_w, fln_b, pooled);

    // 12) G5 split-K(4): h1 = gelu(pooled @ mlp_w1 + b1) -> bf16 [256,4096]
    mfma_gemm_splitk<false><<<dim3(HID / 128, POOLED_ROWS / 128, 4), blk256, 0, stream>>>(
        pooled, DMODEL, m1t, DMODEL, DMODEL / 4, g5part, HID, (size_t)POOLED_ROWS * HID);
    reduce_splitk<4, 1><<<(POOLED_ROWS * HID) / 256, blk256, 0, stream>>>(
        g5part, (size_t)POOLED_ROWS * HID, HID, POOLED_ROWS, HID, nullptr, h1_bf, HID, mlp_b1);

    // 13) G6 split-K(8): out = h1 @ mlp_w2 + b2 -> fp32 [256,4096]
    mfma_gemm_splitk<false><<<dim3(HID / 128, POOLED_ROWS / 128, 8), blk256, 0, stream>>>(
        h1_bf, HID, m2t, HID, HID / 8, g6part, HID, (size_t)POOLED_ROWS * HID);
    reduce_splitk<8, 2><<<(POOLED_ROWS * HID) / 256, blk256, 0, stream>>>(
        g6part, (size_t)POOLED_ROWS * HID, HID, POOLED_ROWS, HID, out, nullptr, HID, mlp_b2);
}